// Round 2
// baseline (9813.718 us; speedup 1.0000x reference)
//
#include <hip/hip_runtime.h>
#include <cstdint>

// Problem constants: B=2, T=2048, C=1024, H=16, D=64, TOP_K=256
// feat_keep = ceil(D*min(TOP_K,T)/T) = ceil(64*256/2048) = 8
constexpr int Tn = 2048;
constexpr int Cn = 1024;
constexpr int Hn = 16;
constexpr int Dn = 64;
constexpr int Mn = 4096;          // B*T
constexpr int KKEEP = 256;        // row-wise top-k
constexpr int FKEEP = 8;          // feature top-k
constexpr unsigned U_NEG_INF = 0x007FFFFFu;  // umap(-inf)

// Order-preserving fp32 -> uint32 map (monotonic incl. +-inf; no NaNs here).
__device__ __forceinline__ unsigned umap(float f) {
    unsigned b = __float_as_uint(f);
    return (b & 0x80000000u) ? ~b : (b | 0x80000000u);
}
__device__ __forceinline__ float uunmap(unsigned u) {
    return __uint_as_float((u & 0x80000000u) ? (u ^ 0x80000000u) : ~u);
}

// ---------------------------------------------------------------------------
// fp32 GEMM: O[m][n] = sum_k A[m][k] * W[n][k]   (A: 4096x1024, W: 1024x1024)
// 128x128 tile, Kc=16, 256 threads, 8x8 microtile. blockIdx.z selects W/O.
// ---------------------------------------------------------------------------
constexpr int TM = 128, TN = 128, TK = 16;

__global__ __launch_bounds__(256)
void gemm_nt_f32(const float* __restrict__ A,
                 const float* __restrict__ W0, const float* __restrict__ W1,
                 const float* __restrict__ W2,
                 float* __restrict__ O0, float* __restrict__ O1,
                 float* __restrict__ O2)
{
    const float* Wm = (blockIdx.z == 0) ? W0 : (blockIdx.z == 1 ? W1 : W2);
    float*       O  = (blockIdx.z == 0) ? O0 : (blockIdx.z == 1 ? O1 : O2);

    __shared__ float As[TK][TM];   // [k][m]
    __shared__ float Bs[TK][TN];   // [k][n]

    const int tid = threadIdx.x;
    const int tx = tid & 15, ty = tid >> 4;
    const int m0 = blockIdx.y * TM;
    const int n0 = blockIdx.x * TN;

    float acc[8][8] = {};

    for (int k0 = 0; k0 < Cn; k0 += TK) {
        __syncthreads();
        // stage 128 rows x 16 k of A and W (2 float4 per thread each)
#pragma unroll
        for (int r = 0; r < 2; ++r) {
            const int f = tid + r * 256;      // 0..511
            const int row = f >> 2, q = f & 3;
            const float4 av = *(const float4*)&A[(size_t)(m0 + row) * Cn + k0 + q * 4];
            As[q * 4 + 0][row] = av.x; As[q * 4 + 1][row] = av.y;
            As[q * 4 + 2][row] = av.z; As[q * 4 + 3][row] = av.w;
            const float4 wv = *(const float4*)&Wm[(size_t)(n0 + row) * Cn + k0 + q * 4];
            Bs[q * 4 + 0][row] = wv.x; Bs[q * 4 + 1][row] = wv.y;
            Bs[q * 4 + 2][row] = wv.z; Bs[q * 4 + 3][row] = wv.w;
        }
        __syncthreads();
#pragma unroll
        for (int kk = 0; kk < TK; ++kk) {
            float a[8], b[8];
            *(float4*)&a[0] = *(const float4*)&As[kk][ty * 8];
            *(float4*)&a[4] = *(const float4*)&As[kk][ty * 8 + 4];
            *(float4*)&b[0] = *(const float4*)&Bs[kk][tx * 8];
            *(float4*)&b[4] = *(const float4*)&Bs[kk][tx * 8 + 4];
#pragma unroll
            for (int i = 0; i < 8; ++i)
#pragma unroll
                for (int j = 0; j < 8; ++j)
                    acc[i][j] += a[i] * b[j];
        }
    }

#pragma unroll
    for (int i = 0; i < 8; ++i) {
        float* dst = &O[(size_t)(m0 + ty * 8 + i) * Cn + n0 + tx * 8];
        float4 o0 = make_float4(acc[i][0], acc[i][1], acc[i][2], acc[i][3]);
        float4 o1 = make_float4(acc[i][4], acc[i][5], acc[i][6], acc[i][7]);
        *(float4*)&dst[0] = o0;
        *(float4*)&dst[4] = o1;
    }
}

// ---------------------------------------------------------------------------
// Feature sparsify: per 64-elem head vector keep |v| >= 8th-largest |v|.
// One wave per vector; Q,K,V in-place.  3*65536 vectors total.
// ---------------------------------------------------------------------------
__global__ __launch_bounds__(256)
void sparsify_topk(float* __restrict__ Q, float* __restrict__ K,
                   float* __restrict__ V)
{
    const int wid  = (blockIdx.x * 256 + threadIdx.x) >> 6;  // global wave id
    const int lane = threadIdx.x & 63;
    const int tensor = wid >> 16;        // 65536 vectors per tensor
    const int vec    = wid & 65535;
    float* base = (tensor == 0) ? Q : (tensor == 1 ? K : V);

    const size_t off = (size_t)vec * 64 + lane;
    const float v = base[off];
    const float a = fabsf(v);

    int cnt = 0;   // # strictly greater than mine
#pragma unroll
    for (int j = 0; j < 64; ++j) {
        const float aj = __shfl(a, j);
        cnt += (aj > a) ? 1 : 0;
    }
    // kth = min over values with fewer than FKEEP strictly-greater = 8th largest
    float cand = (cnt < FKEEP) ? a : 3.402823466e38f;
#pragma unroll
    for (int o = 32; o; o >>= 1) cand = fminf(cand, __shfl_xor(cand, o));
    base[off] = (a >= cand) ? v : 0.0f;
}

// ---------------------------------------------------------------------------
// Attention core: block = 1024 threads = 16 waves; wave w owns query row
// t = blockIdx.x*16 + w for head (b,h) = blockIdx.y.  K staged in LDS tiles
// of 128 cols (stride 65 -> conflict-free gather).  Scores (u-mapped) live in
// 32 regs/lane (col = i*64+lane).  Exact top-256 via MSB bit-descent.
//
// __launch_bounds__(1024, 4): 4 waves/EU -> 1 block/CU -> 128-VGPR budget so
// u[32] stays in registers.  (R1: default budget was 64 VGPR -> u[] spilled
// to scratch -> 39.5 GB HBM writes, 9.2 ms.)
// ---------------------------------------------------------------------------
__global__ __launch_bounds__(1024, 4)
void attn_kernel(const float* __restrict__ Qm, const float* __restrict__ Km,
                 const float* __restrict__ Vm, float* __restrict__ AO)
{
    __shared__ float ktile[128][65];     // 33.3 KB, pad 65 -> 2-way max (free)
    __shared__ float qval_s[16][64];
    __shared__ int   qidx_s[16][64];

    const int tid  = threadIdx.x;
    const int w    = tid >> 6;
    const int lane = tid & 63;
    const int bh   = blockIdx.y;         // 0..31
    const int b    = bh >> 4;
    const int h    = bh & 15;
    const int tile = blockIdx.x;         // 0..127
    const int t    = tile * 16 + w;
    const size_t rowoff = (size_t)(b * Tn + t) * Cn + h * Dn;
    const size_t kvoff  = (size_t)(b * Tn) * Cn + h * Dn;

    // ---- load + compact sparse q row (fold in 1/sqrt(D)=0.125) ----
    const float qv = Qm[rowoff + lane];
    const unsigned long long nzm = __ballot(qv != 0.0f);
    const int pos = __popcll(nzm & ((1ull << lane) - 1ull));
    if (qv != 0.0f) {
        qval_s[w][pos] = qv * 0.125f;
        qidx_s[w][pos] = lane;
    }
    const int nnz = __popcll(nzm);       // wave-uniform

    unsigned u[32];
#pragma unroll
    for (int i = 0; i < 32; ++i) u[i] = U_NEG_INF;

    const int tmax   = tile * 16 + 15;
    const int ntiles = (tmax >> 7) + 1;  // block-uniform

#pragma unroll
    for (int it = 0; it < 16; ++it) {
        if (it < ntiles) {               // block-uniform branch (barriers OK)
            const int s0 = it << 7;
            __syncthreads();
#pragma unroll
            for (int r = 0; r < 2; ++r) {
                const int f = tid + r * 1024;      // 0..2047
                const int col = f >> 4, q = f & 15;
                const float4 k4 = *(const float4*)&Km[kvoff + (size_t)(s0 + col) * Cn + q * 4];
                ktile[col][q * 4 + 0] = k4.x;
                ktile[col][q * 4 + 1] = k4.y;
                ktile[col][q * 4 + 2] = k4.z;
                ktile[col][q * 4 + 3] = k4.w;
            }
            __syncthreads();
            float sc0 = 0.0f, sc1 = 0.0f;
            for (int m = 0; m < nnz; ++m) {
                const float qm = qval_s[w][m];     // broadcast reads
                const int   qi = qidx_s[w][m];
                sc0 += qm * ktile[lane][qi];       // 2-way bank alias: free
                sc1 += qm * ktile[64 + lane][qi];
            }
            u[2 * it + 0] = (s0 + lane      <= t) ? umap(sc0) : U_NEG_INF;
            u[2 * it + 1] = (s0 + 64 + lane <= t) ? umap(sc1) : U_NEG_INF;
        }
    }

    // ---- exact 256th-largest via bit-descent (rows t<256 keep all) ----
    unsigned cur;
    if (t < KKEEP) {
        cur = U_NEG_INF;
    } else {
        cur = 0u;
#pragma unroll 1
        for (int bit = 31; bit >= 0; --bit) {
            const unsigned test = cur | (1u << bit);
            int c = 0;
#pragma unroll
            for (int i = 0; i < 32; ++i) c += (u[i] >= test) ? 1 : 0;
#pragma unroll
            for (int o = 32; o; o >>= 1) c += __shfl_xor(c, o);
            if (c >= KKEEP) cur = test;
        }
    }

    // ---- softmax over kept entries ----
    unsigned mu = 0u;
#pragma unroll
    for (int i = 0; i < 32; ++i) mu = (u[i] > mu) ? u[i] : mu;
#pragma unroll
    for (int o = 32; o; o >>= 1) {
        const unsigned m2 = __shfl_xor(mu, o);
        mu = (m2 > mu) ? m2 : mu;
    }
    const float fm = uunmap(mu);         // row max (always finite: col 0 <= t)

    float ps = 0.0f;
#pragma unroll
    for (int i = 0; i < 32; ++i) {
        const float f  = uunmap(u[i]);
        const float pv = (u[i] >= cur) ? __expf(f - fm) : 0.0f;  // exp(-inf)=0
        u[i] = __float_as_uint(pv);      // reuse regs for probabilities
        ps += pv;
    }
#pragma unroll
    for (int o = 32; o; o >>= 1) ps += __shfl_xor(ps, o);
    const float inv = 1.0f / ps;         // ps >= 1

    // ---- PV: weighted gather of kept V rows (2-deep load pipeline) ----
    float acc = 0.0f;
    const float* __restrict__ vcol = Vm + kvoff + lane;
#pragma unroll
    for (int i = 0; i < 32; ++i) {
        const float pv = __uint_as_float(u[i]);
        unsigned long long m = __ballot(pv > 0.0f);   // wave-uniform
        const int cb = i * 64;
        while (m) {
            const int l0 = __builtin_ctzll(m); m &= m - 1;
            const float w0 = __shfl(pv, l0);
            const float v0 = vcol[(size_t)(cb + l0) * Cn];
            float w1 = 0.0f, v1 = 0.0f;
            if (m) {
                const int l1 = __builtin_ctzll(m); m &= m - 1;
                w1 = __shfl(pv, l1);
                v1 = vcol[(size_t)(cb + l1) * Cn];
            }
            acc += w0 * v0;
            acc += w1 * v1;
        }
    }
    AO[rowoff + lane] = acc * inv;
}

// ---------------------------------------------------------------------------
extern "C" void kernel_launch(void* const* d_in, const int* in_sizes, int n_in,
                              void* d_out, int out_size, void* d_ws, size_t ws_size,
                              hipStream_t stream)
{
    const float* x  = (const float*)d_in[0];
    const float* Wq = (const float*)d_in[1];
    const float* Wk = (const float*)d_in[2];
    const float* Wv = (const float*)d_in[3];
    const float* Wo = (const float*)d_in[4];
    float* out = (float*)d_out;

    float* Q  = (float*)d_ws;            // 4 buffers x 4194304 floats = 64 MB
    float* K  = Q + (size_t)Mn * Cn;
    float* V  = K + (size_t)Mn * Cn;
    float* AO = V + (size_t)Mn * Cn;

    // 1) Q/K/V projections (fp32)
    gemm_nt_f32<<<dim3(Cn / TN, Mn / TM, 3), 256, 0, stream>>>(
        x, Wq, Wk, Wv, Q, K, V);

    // 2) feature top-8 sparsification, in place
    sparsify_topk<<<dim3(3 * 65536 / 4), 256, 0, stream>>>(Q, K, V);

    // 3) sparse attention core -> AO in [B,T,H,D] (== [B,T,C]) layout
    attn_kernel<<<dim3(Tn / 16, 32), 1024, 0, stream>>>(Q, K, V, AO);

    // 4) output projection (fp32)
    gemm_nt_f32<<<dim3(Cn / TN, Mn / TM, 1), 256, 0, stream>>>(
        AO, Wo, Wo, Wo, out, out, out);
}

// Round 3
// 9606.717 us; speedup vs baseline: 1.0215x; 1.0215x over previous
//
#include <hip/hip_runtime.h>
#include <cstdint>

// Problem constants: B=2, T=2048, C=1024, H=16, D=64, TOP_K=256
// feat_keep = ceil(D*min(TOP_K,T)/T) = ceil(64*256/2048) = 8
constexpr int Tn = 2048;
constexpr int Cn = 1024;
constexpr int Hn = 16;
constexpr int Dn = 64;
constexpr int Mn = 4096;          // B*T
constexpr int KKEEP = 256;        // row-wise top-k
constexpr int FKEEP = 8;          // feature top-k
constexpr unsigned U_NEG_INF = 0x007FFFFFu;  // umap(-inf)

// Score storage as a single SSA vector value: R1/R2 post-mortem showed
// `unsigned u[32]` never got promoted out of its alloca (VGPR_Count=56,
// 39.5 GB scratch writes). A vector local is one SSA value -> mem2reg
// promotes it wholesale; subscripts become constant insert/extractelement
// after unrolling. This CANNOT live on the stack.
typedef unsigned uvec32 __attribute__((ext_vector_type(32)));

// Order-preserving fp32 -> uint32 map (monotonic incl. +-inf; no NaNs here).
__device__ __forceinline__ unsigned umap(float f) {
    unsigned b = __float_as_uint(f);
    return (b & 0x80000000u) ? ~b : (b | 0x80000000u);
}
__device__ __forceinline__ float uunmap(unsigned u) {
    return __uint_as_float((u & 0x80000000u) ? (u ^ 0x80000000u) : ~u);
}

// ---------------------------------------------------------------------------
// fp32 GEMM: O[m][n] = sum_k A[m][k] * W[n][k]   (A: 4096x1024, W: 1024x1024)
// 128x128 tile, Kc=16, 256 threads, 8x8 microtile. blockIdx.z selects W/O.
// ---------------------------------------------------------------------------
constexpr int TM = 128, TN = 128, TK = 16;

__global__ __launch_bounds__(256)
void gemm_nt_f32(const float* __restrict__ A,
                 const float* __restrict__ W0, const float* __restrict__ W1,
                 const float* __restrict__ W2,
                 float* __restrict__ O0, float* __restrict__ O1,
                 float* __restrict__ O2)
{
    const float* Wm = (blockIdx.z == 0) ? W0 : (blockIdx.z == 1 ? W1 : W2);
    float*       O  = (blockIdx.z == 0) ? O0 : (blockIdx.z == 1 ? O1 : O2);

    __shared__ float As[TK][TM];   // [k][m]
    __shared__ float Bs[TK][TN];   // [k][n]

    const int tid = threadIdx.x;
    const int tx = tid & 15, ty = tid >> 4;
    const int m0 = blockIdx.y * TM;
    const int n0 = blockIdx.x * TN;

    float acc[8][8] = {};

    for (int k0 = 0; k0 < Cn; k0 += TK) {
        __syncthreads();
        // stage 128 rows x 16 k of A and W (2 float4 per thread each)
#pragma unroll
        for (int r = 0; r < 2; ++r) {
            const int f = tid + r * 256;      // 0..511
            const int row = f >> 2, q = f & 3;
            const float4 av = *(const float4*)&A[(size_t)(m0 + row) * Cn + k0 + q * 4];
            As[q * 4 + 0][row] = av.x; As[q * 4 + 1][row] = av.y;
            As[q * 4 + 2][row] = av.z; As[q * 4 + 3][row] = av.w;
            const float4 wv = *(const float4*)&Wm[(size_t)(n0 + row) * Cn + k0 + q * 4];
            Bs[q * 4 + 0][row] = wv.x; Bs[q * 4 + 1][row] = wv.y;
            Bs[q * 4 + 2][row] = wv.z; Bs[q * 4 + 3][row] = wv.w;
        }
        __syncthreads();
#pragma unroll
        for (int kk = 0; kk < TK; ++kk) {
            float a[8], b[8];
            *(float4*)&a[0] = *(const float4*)&As[kk][ty * 8];
            *(float4*)&a[4] = *(const float4*)&As[kk][ty * 8 + 4];
            *(float4*)&b[0] = *(const float4*)&Bs[kk][tx * 8];
            *(float4*)&b[4] = *(const float4*)&Bs[kk][tx * 8 + 4];
#pragma unroll
            for (int i = 0; i < 8; ++i)
#pragma unroll
                for (int j = 0; j < 8; ++j)
                    acc[i][j] += a[i] * b[j];
        }
    }

#pragma unroll
    for (int i = 0; i < 8; ++i) {
        float* dst = &O[(size_t)(m0 + ty * 8 + i) * Cn + n0 + tx * 8];
        float4 o0 = make_float4(acc[i][0], acc[i][1], acc[i][2], acc[i][3]);
        float4 o1 = make_float4(acc[i][4], acc[i][5], acc[i][6], acc[i][7]);
        *(float4*)&dst[0] = o0;
        *(float4*)&dst[4] = o1;
    }
}

// ---------------------------------------------------------------------------
// Feature sparsify: per 64-elem head vector keep |v| >= 8th-largest |v|.
// One wave per vector; Q,K,V in-place.  3*65536 vectors total.
// ---------------------------------------------------------------------------
__global__ __launch_bounds__(256)
void sparsify_topk(float* __restrict__ Q, float* __restrict__ K,
                   float* __restrict__ V)
{
    const int wid  = (blockIdx.x * 256 + threadIdx.x) >> 6;  // global wave id
    const int lane = threadIdx.x & 63;
    const int tensor = wid >> 16;        // 65536 vectors per tensor
    const int vec    = wid & 65535;
    float* base = (tensor == 0) ? Q : (tensor == 1 ? K : V);

    const size_t off = (size_t)vec * 64 + lane;
    const float v = base[off];
    const float a = fabsf(v);

    int cnt = 0;   // # strictly greater than mine
#pragma unroll
    for (int j = 0; j < 64; ++j) {
        const float aj = __shfl(a, j);
        cnt += (aj > a) ? 1 : 0;
    }
    // kth = min over values with fewer than FKEEP strictly-greater = 8th largest
    float cand = (cnt < FKEEP) ? a : 3.402823466e38f;
#pragma unroll
    for (int o = 32; o; o >>= 1) cand = fminf(cand, __shfl_xor(cand, o));
    base[off] = (a >= cand) ? v : 0.0f;
}

// ---------------------------------------------------------------------------
// Attention core: block = 1024 threads = 16 waves; wave w owns query row
// t = blockIdx.x*16 + w for head (b,h) = blockIdx.y.  K staged in LDS tiles
// of 128 cols (stride 65 -> conflict-free gather).  Scores (u-mapped) live in
// a 32-wide register vector (col = i*64+lane).  Exact top-256 via bit-descent.
//
// __launch_bounds__(1024, 4): 1 block/CU, 128-VGPR budget for the 32-wide
// score vector + ~50 others.
// ---------------------------------------------------------------------------
__global__ __launch_bounds__(1024, 4)
void attn_kernel(const float* __restrict__ Qm, const float* __restrict__ Km,
                 const float* __restrict__ Vm, float* __restrict__ AO)
{
    __shared__ float ktile[128][65];     // 33.3 KB, pad 65 -> 2-way max (free)
    __shared__ float qval_s[16][64];
    __shared__ int   qidx_s[16][64];

    const int tid  = threadIdx.x;
    const int w    = tid >> 6;
    const int lane = tid & 63;
    const int bh   = blockIdx.y;         // 0..31
    const int b    = bh >> 4;
    const int h    = bh & 15;
    const int tile = blockIdx.x;         // 0..127
    const int t    = tile * 16 + w;
    const size_t rowoff = (size_t)(b * Tn + t) * Cn + h * Dn;
    const size_t kvoff  = (size_t)(b * Tn) * Cn + h * Dn;

    // ---- load + compact sparse q row (fold in 1/sqrt(D)=0.125) ----
    const float qv = Qm[rowoff + lane];
    const unsigned long long nzm = __ballot(qv != 0.0f);
    const int pos = __popcll(nzm & ((1ull << lane) - 1ull));
    if (qv != 0.0f) {
        qval_s[w][pos] = qv * 0.125f;
        qidx_s[w][pos] = lane;
    }
    const int nnz = __popcll(nzm);       // wave-uniform

    uvec32 u;
#pragma unroll
    for (int i = 0; i < 32; ++i) u[i] = U_NEG_INF;

    const int tmax   = tile * 16 + 15;
    const int ntiles = (tmax >> 7) + 1;  // block-uniform

#pragma unroll
    for (int it = 0; it < 16; ++it) {
        if (it < ntiles) {               // block-uniform branch (barriers OK)
            const int s0 = it << 7;
            __syncthreads();
#pragma unroll
            for (int r = 0; r < 2; ++r) {
                const int f = tid + r * 1024;      // 0..2047
                const int col = f >> 4, q = f & 15;
                const float4 k4 = *(const float4*)&Km[kvoff + (size_t)(s0 + col) * Cn + q * 4];
                ktile[col][q * 4 + 0] = k4.x;
                ktile[col][q * 4 + 1] = k4.y;
                ktile[col][q * 4 + 2] = k4.z;
                ktile[col][q * 4 + 3] = k4.w;
            }
            __syncthreads();
            float sc0 = 0.0f, sc1 = 0.0f;
            for (int m = 0; m < nnz; ++m) {
                const float qm = qval_s[w][m];     // broadcast reads
                const int   qi = qidx_s[w][m];
                sc0 += qm * ktile[lane][qi];       // 2-way bank alias: free
                sc1 += qm * ktile[64 + lane][qi];
            }
            u[2 * it + 0] = (s0 + lane      <= t) ? umap(sc0) : U_NEG_INF;
            u[2 * it + 1] = (s0 + 64 + lane <= t) ? umap(sc1) : U_NEG_INF;
        }
    }

    // ---- exact 256th-largest via bit-descent (rows t<256 keep all) ----
    unsigned cur;
    if (t < KKEEP) {
        cur = U_NEG_INF;
    } else {
        cur = 0u;
#pragma unroll 1
        for (int bit = 31; bit >= 0; --bit) {
            const unsigned test = cur | (1u << bit);
            int c = 0;
#pragma unroll
            for (int i = 0; i < 32; ++i) c += (u[i] >= test) ? 1 : 0;
#pragma unroll
            for (int o = 32; o; o >>= 1) c += __shfl_xor(c, o);
            if (c >= KKEEP) cur = test;
        }
    }

    // ---- softmax over kept entries ----
    unsigned mu = 0u;
#pragma unroll
    for (int i = 0; i < 32; ++i) mu = (u[i] > mu) ? u[i] : mu;
#pragma unroll
    for (int o = 32; o; o >>= 1) {
        const unsigned m2 = __shfl_xor(mu, o);
        mu = (m2 > mu) ? m2 : mu;
    }
    const float fm = uunmap(mu);         // row max (always finite: col 0 <= t)

    float ps = 0.0f;
#pragma unroll
    for (int i = 0; i < 32; ++i) {
        const float f  = uunmap(u[i]);
        const float pv = (u[i] >= cur) ? __expf(f - fm) : 0.0f;  // exp(-inf)=0
        u[i] = __float_as_uint(pv);      // reuse regs for probabilities
        ps += pv;
    }
#pragma unroll
    for (int o = 32; o; o >>= 1) ps += __shfl_xor(ps, o);
    const float inv = 1.0f / ps;         // ps >= 1

    // ---- PV: weighted gather of kept V rows ----
    float acc = 0.0f;
    const float* __restrict__ vcol = Vm + kvoff + lane;
#pragma unroll
    for (int i = 0; i < 32; ++i) {
        const float pv = __uint_as_float(u[i]);
        unsigned long long m = __ballot(pv > 0.0f);   // wave-uniform
        const int cb = i * 64;
        while (m) {
            const int l0 = __builtin_ctzll(m); m &= m - 1;
            const float w0 = __shfl(pv, l0);
            const float v0 = vcol[(size_t)(cb + l0) * Cn];
            float w1 = 0.0f, v1 = 0.0f;
            if (m) {
                const int l1 = __builtin_ctzll(m); m &= m - 1;
                w1 = __shfl(pv, l1);
                v1 = vcol[(size_t)(cb + l1) * Cn];
            }
            acc += w0 * v0;
            acc += w1 * v1;
        }
    }
    AO[rowoff + lane] = acc * inv;
}

// ---------------------------------------------------------------------------
extern "C" void kernel_launch(void* const* d_in, const int* in_sizes, int n_in,
                              void* d_out, int out_size, void* d_ws, size_t ws_size,
                              hipStream_t stream)
{
    const float* x  = (const float*)d_in[0];
    const float* Wq = (const float*)d_in[1];
    const float* Wk = (const float*)d_in[2];
    const float* Wv = (const float*)d_in[3];
    const float* Wo = (const float*)d_in[4];
    float* out = (float*)d_out;

    float* Q  = (float*)d_ws;            // 4 buffers x 4194304 floats = 64 MB
    float* K  = Q + (size_t)Mn * Cn;
    float* V  = K + (size_t)Mn * Cn;
    float* AO = V + (size_t)Mn * Cn;

    // 1) Q/K/V projections (fp32)
    gemm_nt_f32<<<dim3(Cn / TN, Mn / TM, 3), 256, 0, stream>>>(
        x, Wq, Wk, Wv, Q, K, V);

    // 2) feature top-8 sparsification, in place
    sparsify_topk<<<dim3(3 * 65536 / 4), 256, 0, stream>>>(Q, K, V);

    // 3) sparse attention core -> AO in [B,T,H,D] (== [B,T,C]) layout
    attn_kernel<<<dim3(Tn / 16, 32), 1024, 0, stream>>>(Q, K, V, AO);

    // 4) output projection (fp32)
    gemm_nt_f32<<<dim3(Cn / TN, Mn / TM, 1), 256, 0, stream>>>(
        AO, Wo, Wo, Wo, out, out, out);
}

// Round 4
// 1799.272 us; speedup vs baseline: 5.4543x; 5.3392x over previous
//
#include <hip/hip_runtime.h>
#include <cstdint>

// Problem constants: B=2, T=2048, C=1024, H=16, D=64, TOP_K=256
// feat_keep = ceil(D*min(TOP_K,T)/T) = ceil(64*256/2048) = 8
constexpr int Tn = 2048;
constexpr int Cn = 1024;
constexpr int Dn = 64;
constexpr int Mn = 4096;          // B*T
constexpr int KKEEP = 256;        // row-wise top-k
constexpr int FKEEP = 8;          // feature top-k
constexpr unsigned U_NEG_INF = 0x007FFFFFu;  // umap(-inf)

// Chunked score-row layout in LDS: 64 chunks of 32 values + 1 pad word each.
// All phase access patterns land <=2-way bank aliasing (free on CDNA4).
constexpr int SC_ROW = 64 * 33;   // 2112 words per query row
__device__ __forceinline__ int sc_addr(int col) { return (col >> 5) * 33 + (col & 31); }

// Order-preserving fp32 -> uint32 map (monotonic incl. +-inf; no NaNs here).
__device__ __forceinline__ unsigned umap(float f) {
    unsigned b = __float_as_uint(f);
    return (b & 0x80000000u) ? ~b : (b | 0x80000000u);
}
__device__ __forceinline__ float uunmap(unsigned u) {
    return __uint_as_float((u & 0x80000000u) ? (u ^ 0x80000000u) : ~u);
}

// ---------------------------------------------------------------------------
// fp32 GEMM: O[m][n] = sum_k A[m][k] * W[n][k]   (A: 4096x1024, W: 1024x1024)
// 128x128 tile, Kc=16, 256 threads, 8x8 microtile. blockIdx.z selects W/O.
// ---------------------------------------------------------------------------
constexpr int TM = 128, TN = 128, TK = 16;

__global__ __launch_bounds__(256)
void gemm_nt_f32(const float* __restrict__ A,
                 const float* __restrict__ W0, const float* __restrict__ W1,
                 const float* __restrict__ W2,
                 float* __restrict__ O0, float* __restrict__ O1,
                 float* __restrict__ O2)
{
    const float* Wm = (blockIdx.z == 0) ? W0 : (blockIdx.z == 1 ? W1 : W2);
    float*       O  = (blockIdx.z == 0) ? O0 : (blockIdx.z == 1 ? O1 : O2);

    __shared__ float As[TK][TM];   // [k][m]
    __shared__ float Bs[TK][TN];   // [k][n]

    const int tid = threadIdx.x;
    const int tx = tid & 15, ty = tid >> 4;
    const int m0 = blockIdx.y * TM;
    const int n0 = blockIdx.x * TN;

    float acc[8][8] = {};

    for (int k0 = 0; k0 < Cn; k0 += TK) {
        __syncthreads();
#pragma unroll
        for (int r = 0; r < 2; ++r) {
            const int f = tid + r * 256;      // 0..511
            const int row = f >> 2, q = f & 3;
            const float4 av = *(const float4*)&A[(size_t)(m0 + row) * Cn + k0 + q * 4];
            As[q * 4 + 0][row] = av.x; As[q * 4 + 1][row] = av.y;
            As[q * 4 + 2][row] = av.z; As[q * 4 + 3][row] = av.w;
            const float4 wv = *(const float4*)&Wm[(size_t)(n0 + row) * Cn + k0 + q * 4];
            Bs[q * 4 + 0][row] = wv.x; Bs[q * 4 + 1][row] = wv.y;
            Bs[q * 4 + 2][row] = wv.z; Bs[q * 4 + 3][row] = wv.w;
        }
        __syncthreads();
#pragma unroll
        for (int kk = 0; kk < TK; ++kk) {
            float a[8], b[8];
            *(float4*)&a[0] = *(const float4*)&As[kk][ty * 8];
            *(float4*)&a[4] = *(const float4*)&As[kk][ty * 8 + 4];
            *(float4*)&b[0] = *(const float4*)&Bs[kk][tx * 8];
            *(float4*)&b[4] = *(const float4*)&Bs[kk][tx * 8 + 4];
#pragma unroll
            for (int i = 0; i < 8; ++i)
#pragma unroll
                for (int j = 0; j < 8; ++j)
                    acc[i][j] += a[i] * b[j];
        }
    }

#pragma unroll
    for (int i = 0; i < 8; ++i) {
        float* dst = &O[(size_t)(m0 + ty * 8 + i) * Cn + n0 + tx * 8];
        float4 o0 = make_float4(acc[i][0], acc[i][1], acc[i][2], acc[i][3]);
        float4 o1 = make_float4(acc[i][4], acc[i][5], acc[i][6], acc[i][7]);
        *(float4*)&dst[0] = o0;
        *(float4*)&dst[4] = o1;
    }
}

// ---------------------------------------------------------------------------
// Feature sparsify: per 64-elem head vector keep |v| >= 8th-largest |v|.
// One wave per vector; Q,K,V in-place.  3*65536 vectors total.
// ---------------------------------------------------------------------------
__global__ __launch_bounds__(256)
void sparsify_topk(float* __restrict__ Q, float* __restrict__ K,
                   float* __restrict__ V)
{
    const int wid  = (blockIdx.x * 256 + threadIdx.x) >> 6;  // global wave id
    const int lane = threadIdx.x & 63;
    const int tensor = wid >> 16;        // 65536 vectors per tensor
    const int vec    = wid & 65535;
    float* base = (tensor == 0) ? Q : (tensor == 1 ? K : V);

    const size_t off = (size_t)vec * 64 + lane;
    const float v = base[off];
    const float a = fabsf(v);

    int cnt = 0;   // # strictly greater than mine
#pragma unroll
    for (int j = 0; j < 64; ++j) {
        const float aj = __shfl(a, j);
        cnt += (aj > a) ? 1 : 0;
    }
    float cand = (cnt < FKEEP) ? a : 3.402823466e38f;
#pragma unroll
    for (int o = 32; o; o >>= 1) cand = fminf(cand, __shfl_xor(cand, o));
    base[off] = (a >= cand) ? v : 0.0f;
}

// ---------------------------------------------------------------------------
// Attention core, R4: scores live in LDS (no per-thread aggregate -> nothing
// for the compiler to put in scratch; R1-R3 all burned 39.5 GB of HBM on a
// scratch-resident score array at identical VGPR_Count=56).
//
// Block = 1024 thr = 16 waves; wave w owns query row t = blockIdx.x*16 + w.
// LDS (dynamic, 160000 B): sc[16][SC_ROW] umapped scores, kt[64][65] K tile,
// qv/qi[16][64] compacted sparse q.  Exact top-256 via bit-descent with
// exact early exit (count==K => kept set == ref's {score >= kth}).
// ---------------------------------------------------------------------------
__global__ __launch_bounds__(1024, 4)
void attn_kernel(const float* __restrict__ Qm, const float* __restrict__ Km,
                 const float* __restrict__ Vm, float* __restrict__ AO)
{
    extern __shared__ unsigned smem[];
    unsigned* sc = smem;                              // 16*2112 = 33792 words
    float*    kt = (float*)(smem + 16 * SC_ROW);      // 64*65  = 4160 words
    float*    qv = kt + 64 * 65;                      // 16*64
    int*      qi = (int*)(qv + 16 * 64);              // 16*64

    const int tid  = threadIdx.x;
    const int w    = tid >> 6;
    const int lane = tid & 63;
    const int bh   = blockIdx.y;         // 0..31
    const int b    = bh >> 4;
    const int h    = bh & 15;
    const int t    = blockIdx.x * 16 + w;
    const size_t rowoff = (size_t)(b * Tn + t) * Cn + h * Dn;
    const size_t kvoff  = (size_t)(b * Tn) * Cn + h * Dn;

    // ---- load + compact sparse q row (fold in 1/sqrt(D)=0.125) ----
    const float q0 = Qm[rowoff + lane];
    const unsigned long long nzm = __ballot(q0 != 0.0f);
    const int pos = __popcll(nzm & ((1ull << lane) - 1ull));
    if (q0 != 0.0f) { qv[w * 64 + pos] = q0 * 0.125f; qi[w * 64 + pos] = lane; }
    const int nnz = __popcll(nzm);       // wave-uniform

    unsigned* myrow = sc + w * SC_ROW;
    unsigned rowmax = 0u;

    // ---- score phase: 32 K-tiles of 64 cols ----
#pragma unroll 1
    for (int tk = 0; tk < 32; ++tk) {
        const int s0 = tk << 6;
        __syncthreads();
        {   // stage 64 rows x 64 floats of K: one float4 per thread
            const int c = tid >> 4, q4 = (tid & 15) * 4;
            const float4 k4 = *(const float4*)&Km[kvoff + (size_t)(s0 + c) * Cn + q4];
            float* dst = &kt[c * 65 + q4];
            dst[0] = k4.x; dst[1] = k4.y; dst[2] = k4.z; dst[3] = k4.w;
        }
        __syncthreads();
        unsigned val = U_NEG_INF;
        if (s0 <= t) {                   // wave-uniform
            float s = 0.0f;
            for (int m = 0; m < nnz; ++m)
                s += qv[w * 64 + m] * kt[lane * 65 + qi[w * 64 + m]];
            if (s0 + lane <= t) val = umap(s);
        }
        myrow[sc_addr(s0 + lane)] = val;
        rowmax = (val > rowmax) ? val : rowmax;
    }
    __syncthreads();

#pragma unroll
    for (int o = 32; o; o >>= 1) {
        const unsigned m2 = __shfl_xor(rowmax, o);
        rowmax = (m2 > rowmax) ? m2 : rowmax;
    }
    const float fm = uunmap(rowmax);     // row max (finite: col 0 <= t)

    // ---- exact 256th-largest via bit-descent over LDS (early exit) ----
    unsigned cur = U_NEG_INF;            // rows t<256 keep everything
    if (t >= KKEEP) {
        cur = 0u;
#pragma unroll 1
        for (int bit = 31; bit >= 0; --bit) {
            const unsigned test = cur | (1u << bit);
            int c = 0;
            const unsigned* ch = &myrow[lane * 33];  // lane's 32-value chunk
#pragma unroll
            for (int j = 0; j < 32; ++j) c += (ch[j] >= test) ? 1 : 0;
#pragma unroll
            for (int o = 32; o; o >>= 1) c += __shfl_xor(c, o);
            if (c >= KKEEP) {
                cur = test;
                if (c == KKEEP) break;   // exact: {>=test} == top-K == {>=kth}
            }
        }
    }

    // ---- softmax: p = exp(s - max) for kept, 0 else; write p back ----
    float ps = 0.0f;
    {
        unsigned* ch = &myrow[lane * 33];
#pragma unroll
        for (int j = 0; j < 32; ++j) {
            const unsigned uv = ch[j];
            const float pv = (uv >= cur) ? __expf(uunmap(uv) - fm) : 0.0f;
            ch[j] = __float_as_uint(pv);
            ps += pv;
        }
    }
#pragma unroll
    for (int o = 32; o; o >>= 1) ps += __shfl_xor(ps, o);
    const float inv = 1.0f / ps;         // ps >= 1

    // ---- PV: weighted gather of kept V rows (coalesced 256B reads) ----
    float acc = 0.0f;
    const float* __restrict__ vcol = Vm + kvoff + lane;
#pragma unroll 1
    for (int g = 0; g < 32; ++g) {
        const float pv = __uint_as_float(myrow[sc_addr(g * 64 + lane)]);
        unsigned long long m = __ballot(pv > 0.0f);   // wave-uniform
        const int cb = g * 64;
        while (m) {
            const int l0 = __builtin_ctzll(m); m &= m - 1;
            const float w0 = __shfl(pv, l0);
            const float v0 = vcol[(size_t)(cb + l0) * Cn];
            float w1 = 0.0f, v1 = 0.0f;
            if (m) {
                const int l1 = __builtin_ctzll(m); m &= m - 1;
                w1 = __shfl(pv, l1);
                v1 = vcol[(size_t)(cb + l1) * Cn];
            }
            acc += w0 * v0;
            acc += w1 * v1;
        }
    }
    AO[rowoff + lane] = acc * inv;
}

// ---------------------------------------------------------------------------
extern "C" void kernel_launch(void* const* d_in, const int* in_sizes, int n_in,
                              void* d_out, int out_size, void* d_ws, size_t ws_size,
                              hipStream_t stream)
{
    const float* x  = (const float*)d_in[0];
    const float* Wq = (const float*)d_in[1];
    const float* Wk = (const float*)d_in[2];
    const float* Wv = (const float*)d_in[3];
    const float* Wo = (const float*)d_in[4];
    float* out = (float*)d_out;

    float* Q  = (float*)d_ws;            // 4 buffers x 4194304 floats = 64 MB
    float* K  = Q + (size_t)Mn * Cn;
    float* V  = K + (size_t)Mn * Cn;
    float* AO = V + (size_t)Mn * Cn;

    constexpr int ATTN_LDS = (16 * SC_ROW + 64 * 65 + 16 * 64 + 16 * 64) * 4; // 160000 B
    static_assert(ATTN_LDS <= 163840, "LDS over 160 KiB");
    (void)hipFuncSetAttribute((const void*)attn_kernel,
                              hipFuncAttributeMaxDynamicSharedMemorySize, ATTN_LDS);

    // 1) Q/K/V projections (fp32)
    gemm_nt_f32<<<dim3(Cn / TN, Mn / TM, 3), 256, 0, stream>>>(
        x, Wq, Wk, Wv, Q, K, V);

    // 2) feature top-8 sparsification, in place
    sparsify_topk<<<dim3(3 * 65536 / 4), 256, 0, stream>>>(Q, K, V);

    // 3) sparse attention core -> AO in [B,T,H,D] (== [B,T,C]) layout
    attn_kernel<<<dim3(Tn / 16, 32), 1024, ATTN_LDS, stream>>>(Q, K, V, AO);

    // 4) output projection (fp32)
    gemm_nt_f32<<<dim3(Cn / TN, Mn / TM, 1), 256, 0, stream>>>(
        AO, Wo, Wo, Wo, out, out, out);
}

// Round 5
// 1735.640 us; speedup vs baseline: 5.6542x; 1.0367x over previous
//
#include <hip/hip_runtime.h>
#include <cstdint>

// Problem constants: B=2, T=2048, C=1024, H=16, D=64, TOP_K=256
// feat_keep = ceil(D*min(TOP_K,T)/T) = ceil(64*256/2048) = 8
constexpr int Tn = 2048;
constexpr int Cn = 1024;
constexpr int Mn = 4096;          // B*T
constexpr int KKEEP = 256;        // row-wise top-k
constexpr int FKEEP = 8;          // feature top-k
constexpr unsigned U_NEG_INF = 0x007FFFFFu;  // umap(-inf)

// Score row layout in LDS: 64 chunks of 33 words (32 cols + 1 pad).
// Striped access col = j*64+lane -> addr = j*66 + lane_base: <=2-way banks.
constexpr int SC_ROW = 64 * 33;   // 2112 words per query row

// Order-preserving fp32 -> uint32 map (monotonic incl. +-inf; no NaNs here).
__device__ __forceinline__ unsigned umap(float f) {
    unsigned b = __float_as_uint(f);
    return (b & 0x80000000u) ? ~b : (b | 0x80000000u);
}
__device__ __forceinline__ float uunmap(unsigned u) {
    return __uint_as_float((u & 0x80000000u) ? (u ^ 0x80000000u) : ~u);
}

// ---------------------------------------------------------------------------
// fp32 GEMM: O[m][n] = sum_k A[m][k] * W[n][k]   (A: 4096x1024, W: 1024x1024)
// 128x128 tile, Kc=16, 256 threads, 8x8 microtile. blockIdx.z selects W/O.
// ---------------------------------------------------------------------------
constexpr int TM = 128, TN = 128, TK = 16;

__global__ __launch_bounds__(256)
void gemm_nt_f32(const float* __restrict__ A,
                 const float* __restrict__ W0, const float* __restrict__ W1,
                 const float* __restrict__ W2,
                 float* __restrict__ O0, float* __restrict__ O1,
                 float* __restrict__ O2)
{
    const float* Wm = (blockIdx.z == 0) ? W0 : (blockIdx.z == 1 ? W1 : W2);
    float*       O  = (blockIdx.z == 0) ? O0 : (blockIdx.z == 1 ? O1 : O2);

    __shared__ float As[TK][TM];   // [k][m]
    __shared__ float Bs[TK][TN];   // [k][n]

    const int tid = threadIdx.x;
    const int tx = tid & 15, ty = tid >> 4;
    const int m0 = blockIdx.y * TM;
    const int n0 = blockIdx.x * TN;

    float acc[8][8] = {};

    for (int k0 = 0; k0 < Cn; k0 += TK) {
        __syncthreads();
#pragma unroll
        for (int r = 0; r < 2; ++r) {
            const int f = tid + r * 256;      // 0..511
            const int row = f >> 2, q = f & 3;
            const float4 av = *(const float4*)&A[(size_t)(m0 + row) * Cn + k0 + q * 4];
            As[q * 4 + 0][row] = av.x; As[q * 4 + 1][row] = av.y;
            As[q * 4 + 2][row] = av.z; As[q * 4 + 3][row] = av.w;
            const float4 wv = *(const float4*)&Wm[(size_t)(n0 + row) * Cn + k0 + q * 4];
            Bs[q * 4 + 0][row] = wv.x; Bs[q * 4 + 1][row] = wv.y;
            Bs[q * 4 + 2][row] = wv.z; Bs[q * 4 + 3][row] = wv.w;
        }
        __syncthreads();
#pragma unroll
        for (int kk = 0; kk < TK; ++kk) {
            float a[8], b[8];
            *(float4*)&a[0] = *(const float4*)&As[kk][ty * 8];
            *(float4*)&a[4] = *(const float4*)&As[kk][ty * 8 + 4];
            *(float4*)&b[0] = *(const float4*)&Bs[kk][tx * 8];
            *(float4*)&b[4] = *(const float4*)&Bs[kk][tx * 8 + 4];
#pragma unroll
            for (int i = 0; i < 8; ++i)
#pragma unroll
                for (int j = 0; j < 8; ++j)
                    acc[i][j] += a[i] * b[j];
        }
    }

#pragma unroll
    for (int i = 0; i < 8; ++i) {
        float* dst = &O[(size_t)(m0 + ty * 8 + i) * Cn + n0 + tx * 8];
        float4 o0 = make_float4(acc[i][0], acc[i][1], acc[i][2], acc[i][3]);
        float4 o1 = make_float4(acc[i][4], acc[i][5], acc[i][6], acc[i][7]);
        *(float4*)&dst[0] = o0;
        *(float4*)&dst[4] = o1;
    }
}

// ---------------------------------------------------------------------------
// Feature sparsify: per 64-elem head vector keep |v| >= 8th-largest |v|.
// One wave per vector; Q,K,V in-place.  3*65536 vectors total.
// ---------------------------------------------------------------------------
__global__ __launch_bounds__(256)
void sparsify_topk(float* __restrict__ Q, float* __restrict__ K,
                   float* __restrict__ V)
{
    const int wid  = (blockIdx.x * 256 + threadIdx.x) >> 6;  // global wave id
    const int lane = threadIdx.x & 63;
    const int tensor = wid >> 16;        // 65536 vectors per tensor
    const int vec    = wid & 65535;
    float* base = (tensor == 0) ? Q : (tensor == 1 ? K : V);

    const size_t off = (size_t)vec * 64 + lane;
    const float v = base[off];
    const float a = fabsf(v);

    int cnt = 0;   // # strictly greater than mine
#pragma unroll
    for (int j = 0; j < 64; ++j) {
        const float aj = __shfl(a, j);
        cnt += (aj > a) ? 1 : 0;
    }
    float cand = (cnt < FKEEP) ? a : 3.402823466e38f;
#pragma unroll
    for (int o = 32; o; o >>= 1) cand = fminf(cand, __shfl_xor(cand, o));
    base[off] = (a >= cand) ? v : 0.0f;
}

// ---------------------------------------------------------------------------
// Attention core, R5.  Scores in LDS (R4: scratch fix).  New this round:
//  - radix-256 select (8 bits/level, <=4 levels, early exit) replaces the
//    32-iter bit-descent: ~2.5 levels x 17 reads vs ~20 x 32 reads.
//  - visible-only striped loops (col = j*64+lane) in select/softmax/PV.
//  - score phase stages only the tiles this block can see; q broadcast via
//    v_readlane from a register (no qv/qi LDS arrays at all).
// LDS map (dynamic, 151808 B): sc[16][2112] scores | kt[64][65] K tile,
// overlaid after the score phase by hist[16][256].
// Exact top-K semantics: cur = largest u with count(v>=u) >= K  ==> kept set
// {v >= cur} == ref's {score >= kth} including tie behavior.
// ---------------------------------------------------------------------------
__global__ __launch_bounds__(1024, 4)
void attn_kernel(const float* __restrict__ Qm, const float* __restrict__ Km,
                 const float* __restrict__ Vm, float* __restrict__ AO)
{
    extern __shared__ unsigned smem[];
    unsigned* sc   = smem;                         // 16*2112 = 33792 words
    float*    kt   = (float*)(smem + 16 * SC_ROW); // 64*65   =  4160 words
    unsigned* hist = smem + 16 * SC_ROW;           // 16*256  =  4096 words (overlay)

    const int tid  = threadIdx.x;
    const int w    = tid >> 6;
    const int lane = tid & 63;
    const int bh   = blockIdx.y;         // 0..31
    const int b    = bh >> 4;
    const int h    = bh & 15;
    const int t    = blockIdx.x * 16 + w;
    const size_t rowoff = (size_t)(b * Tn + t) * Cn + h * 64;
    const size_t kvoff  = (size_t)(b * Tn) * Cn + h * 64;

    // ---- init all score rows to umap(-inf) (pads too) ----
#pragma unroll
    for (int i = 0; i < 33; ++i) smem[i * 1024 + tid] = U_NEG_INF;

    // ---- sparse q row in a register; nonzero feature mask in SGPRs ----
    const float q0  = Qm[rowoff + lane];
    const float qsc = q0 * 0.125f;                  // fold 1/sqrt(D)
    const unsigned long long nzm = __ballot(q0 != 0.0f);  // wave-uniform

    unsigned* myrow = sc + w * SC_ROW;
    const int lb = (lane >> 5) * 33 + (lane & 31);  // striped lane base
    unsigned rowmax = 0u;

    // ---- score phase: only tiles visible to this block ----
    const int ntiles = ((blockIdx.x * 16 + 15) >> 6) + 1;   // block-uniform
    for (int tk = 0; tk < ntiles; ++tk) {
        const int s0 = tk << 6;
        __syncthreads();                 // also covers the init on tk==0
        {   // stage 64 cols x 64 feats of K: one float4 per thread
            const int c = tid >> 4, q4 = (tid & 15) * 4;
            const float4 k4 = *(const float4*)&Km[kvoff + (size_t)(s0 + c) * Cn + q4];
            float* dst = &kt[c * 65 + q4];
            dst[0] = k4.x; dst[1] = k4.y; dst[2] = k4.z; dst[3] = k4.w;
        }
        __syncthreads();
        if (s0 <= t) {                   // wave-uniform
            float s = 0.0f;
            unsigned long long mm = nzm;
            while (mm) {                 // nnz (~8) iterations, wave-uniform
                const int m = __builtin_ctzll(mm); mm &= mm - 1;
#if __has_builtin(__builtin_amdgcn_readlane)
                const float qm = __int_as_float(
                    __builtin_amdgcn_readlane(__float_as_int(qsc), m));
#else
                const float qm = __shfl(qsc, m);
#endif
                s += qm * kt[lane * 65 + m];   // banks (lane+m)%32: 2-way, free
            }
            unsigned val = U_NEG_INF;
            if (s0 + lane <= t) val = umap(s);
            myrow[tk * 66 + lb] = val;         // col = s0 + lane
            rowmax = (val > rowmax) ? val : rowmax;
        }
    }
    __syncthreads();    // kt dead from here; hist overlay becomes safe

#pragma unroll
    for (int o = 32; o; o >>= 1) {
        const unsigned m2 = __shfl_xor(rowmax, o);
        rowmax = (m2 > rowmax) ? m2 : rowmax;
    }
    const float fm = uunmap(rowmax);     // row max (finite: col 0 <= t)

    const int nj = (t >> 6) + 1;         // visible striped groups, wave-uniform

    // ---- exact kth via radix-256 select over LDS (wave-local, no barriers) ----
    unsigned cur = U_NEG_INF;            // rows t<256 keep everything
    if (t >= KKEEP) {
        unsigned* hrow = hist + w * 256;
        unsigned prefix = 0u, pmask = 0u;
        unsigned r = KKEEP;
#pragma unroll 1
        for (int level = 0; level < 4; ++level) {
            const int sh = 24 - 8 * level;
            hrow[lane] = 0; hrow[64 + lane] = 0; hrow[128 + lane] = 0; hrow[192 + lane] = 0;
            __asm__ volatile("s_waitcnt lgkmcnt(0)" ::: "memory");
#pragma unroll 1
            for (int j = 0; j < nj; ++j) {
                const int col = (j << 6) + lane;
                if (col <= t) {
                    const unsigned v = myrow[j * 66 + lb];
                    if ((v & pmask) == prefix)
                        atomicAdd(&hrow[(v >> sh) & 255u], 1u);
                }
            }
            __asm__ volatile("s_waitcnt lgkmcnt(0)" ::: "memory");
            const uint4 hv = *(const uint4*)&hrow[lane * 4];   // bins 4l..4l+3
            const unsigned ls = hv.x + hv.y + hv.z + hv.w;
            unsigned sfx = ls;                    // inclusive suffix over lanes
#pragma unroll
            for (int off = 1; off < 64; off <<= 1) {
                const unsigned tt = __shfl_down(sfx, off);
                if (lane + off < 64) sfx += tt;
            }
            const unsigned excl = sfx - ls;       // lanes strictly above
            const unsigned c3 = excl + hv.w, c2 = c3 + hv.z,
                           c1 = c2 + hv.y,  c0 = c1 + hv.x;
            // largest in-lane bin with cnt_ge >= r (cnt_ge monotone in bin)
            int bsel = -1; unsigned csel = 0, cnext = 0;
            if      (c3 >= r) { bsel = 4 * lane + 3; csel = c3; cnext = excl; }
            else if (c2 >= r) { bsel = 4 * lane + 2; csel = c2; cnext = c3; }
            else if (c1 >= r) { bsel = 4 * lane + 1; csel = c1; cnext = c2; }
            else if (c0 >= r) { bsel = 4 * lane + 0; csel = c0; cnext = c1; }
            int B = bsel;
#pragma unroll
            for (int off = 32; off; off >>= 1) {
                const int ob = __shfl_xor(B, off);
                B = (ob > B) ? ob : B;
            }
            const unsigned cB  = (unsigned)__shfl((int)csel,  B >> 2);
            const unsigned cB1 = (unsigned)__shfl((int)cnext, B >> 2);
            prefix |= (unsigned)B << sh;
            pmask  |= 255u << sh;
            if (cB == r || level == 3) { cur = prefix; break; }
            r -= cB1;                    // rank within bin B
        }
    }

    // ---- softmax over kept visible entries; write p back ----
    float ps = 0.0f;
#pragma unroll 1
    for (int j = 0; j < nj; ++j) {
        const int col = (j << 6) + lane;
        if (col <= t) {
            const unsigned uv = myrow[j * 66 + lb];
            const float pv = (uv >= cur) ? __expf(uunmap(uv) - fm) : 0.0f;
            myrow[j * 66 + lb] = __float_as_uint(pv);
            ps += pv;
        }
    }
#pragma unroll
    for (int o = 32; o; o >>= 1) ps += __shfl_xor(ps, o);
    const float inv = 1.0f / ps;         // ps >= 1 (row max is kept)

    // ---- PV: weighted gather of kept V rows (coalesced 256B reads) ----
    float acc = 0.0f;
    const float* __restrict__ vcol = Vm + kvoff + lane;
#pragma unroll 1
    for (int g = 0; g < nj; ++g) {
        const int col = (g << 6) + lane;
        const float pv = (col <= t) ? __uint_as_float(myrow[g * 66 + lb]) : 0.0f;
        unsigned long long m = __ballot(pv > 0.0f);   // wave-uniform
        const int cb = g << 6;
        while (m) {
            const int l0 = __builtin_ctzll(m); m &= m - 1;
            const float w0 = __shfl(pv, l0);
            const float v0 = vcol[(size_t)(cb + l0) * Cn];
            float w1 = 0.0f, v1 = 0.0f;
            if (m) {
                const int l1 = __builtin_ctzll(m); m &= m - 1;
                w1 = __shfl(pv, l1);
                v1 = vcol[(size_t)(cb + l1) * Cn];
            }
            acc += w0 * v0;
            acc += w1 * v1;
        }
    }
    AO[rowoff + lane] = acc * inv;
}

// ---------------------------------------------------------------------------
extern "C" void kernel_launch(void* const* d_in, const int* in_sizes, int n_in,
                              void* d_out, int out_size, void* d_ws, size_t ws_size,
                              hipStream_t stream)
{
    const float* x  = (const float*)d_in[0];
    const float* Wq = (const float*)d_in[1];
    const float* Wk = (const float*)d_in[2];
    const float* Wv = (const float*)d_in[3];
    const float* Wo = (const float*)d_in[4];
    float* out = (float*)d_out;

    float* Q  = (float*)d_ws;            // 4 buffers x 4194304 floats = 64 MB
    float* K  = Q + (size_t)Mn * Cn;
    float* V  = K + (size_t)Mn * Cn;
    float* AO = V + (size_t)Mn * Cn;

    constexpr int ATTN_LDS = (16 * SC_ROW + 64 * 65) * 4;   // 151808 B
    static_assert(ATTN_LDS <= 163840, "LDS over 160 KiB");
    static_assert(16 * 256 <= 64 * 65, "hist overlay exceeds kt region");
    (void)hipFuncSetAttribute((const void*)attn_kernel,
                              hipFuncAttributeMaxDynamicSharedMemorySize, ATTN_LDS);

    // 1) Q/K/V projections (fp32)
    gemm_nt_f32<<<dim3(Cn / TN, Mn / TM, 3), 256, 0, stream>>>(
        x, Wq, Wk, Wv, Q, K, V);

    // 2) feature top-8 sparsification, in place
    sparsify_topk<<<dim3(3 * 65536 / 4), 256, 0, stream>>>(Q, K, V);

    // 3) sparse attention core -> AO in [B,T,H,D] (== [B,T,C]) layout
    attn_kernel<<<dim3(Tn / 16, 32), 1024, ATTN_LDS, stream>>>(Q, K, V, AO);

    // 4) output projection (fp32)
    gemm_nt_f32<<<dim3(Cn / TN, Mn / TM, 1), 256, 0, stream>>>(
        AO, Wo, Wo, Wo, out, out, out);
}

// Round 8
// 1408.110 us; speedup vs baseline: 6.9694x; 1.2326x over previous
//
#include <hip/hip_runtime.h>
#include <cstdint>

// Problem constants: B=2, T=2048, C=1024, H=16, D=64, TOP_K=256
// feat_keep = ceil(D*min(TOP_K,T)/T) = ceil(64*256/2048) = 8
constexpr int Tn = 2048;
constexpr int Cn = 1024;
constexpr int Mn = 4096;          // B*T
constexpr int KKEEP = 256;        // row-wise top-k
constexpr int FKEEP = 8;          // feature top-k
constexpr unsigned U_NEG_INF = 0x007FFFFFu;  // umap(-inf)

// Score row layout in LDS: 64 chunks of 33 words (32 cols + 1 pad).
// Striped access col = j*64+lane -> addr = j*66 + lane_base: <=2-way banks.
constexpr int SC_ROW = 64 * 33;   // 2112 words per query row
__device__ __forceinline__ int sc_addr(int col) { return (col >> 5) * 33 + (col & 31); }

// Order-preserving fp32 -> uint32 map (monotonic incl. +-inf; no NaNs here).
__device__ __forceinline__ unsigned umap(float f) {
    unsigned b = __float_as_uint(f);
    return (b & 0x80000000u) ? ~b : (b | 0x80000000u);
}
__device__ __forceinline__ float uunmap(unsigned u) {
    return __uint_as_float((u & 0x80000000u) ? (u ^ 0x80000000u) : ~u);
}

// fp32 -> bf16 (RNE).
__device__ __forceinline__ unsigned short f2bf(float f) {
    unsigned u = __float_as_uint(f);
    u += 0x7FFFu + ((u >> 16) & 1u);
    return (unsigned short)(u >> 16);
}
// Split fp32 into hi+lo bf16 pair (returned by value: ext-vector elements
// cannot bind to non-const refs — R7 compile fail).  x ~= hi + lo, ~17-bit
// effective mantissa.
struct bfpair { unsigned short h, l; };
__device__ __forceinline__ bfpair split_bf16(float x) {
    bfpair r;
    r.h = f2bf(x);
    r.l = f2bf(x - __uint_as_float((unsigned)r.h << 16));
    return r;
}

typedef __attribute__((ext_vector_type(8))) short          short8v;  // 8 bf16
typedef __attribute__((ext_vector_type(8))) unsigned short ushort8v;
typedef __attribute__((ext_vector_type(4))) float          f32x4;    // MFMA acc

// ---------------------------------------------------------------------------
// Split-bf16 MFMA GEMM ("3xBF16"): O[m][n] = sum_k A[m][k] * W[n][k],
// fp32 in/out at ~fp32 accuracy.  Each operand split hi+lo during staging;
// acc += Ah*Bh + Ah*Bl + Al*Bh (lo*lo term ~2^-18, dropped).
// R6 post-mortem: single-bf16 GEMM gave absmax 0.0718 (>thr) — precision,
// not layout (layouts validated by the small-error failure).
// 128x128 tile, BK=32, 256 thr = 4 waves (2x2), 4x4 16x16x32 MFMAs per wave.
//   A-op: lane holds A[m=lane&15][k=(lane>>4)*8+j]  (one b128 read)
//   C/D : col n = lane&15, row m = (lane>>4)*4+reg
// LDS rows padded to 40 ushorts (80 B = 20-word stride -> <=2-way banks).
// blockIdx.z selects W/O (z=3 for QKV, z=1 for out-proj).
// ---------------------------------------------------------------------------
__global__ __launch_bounds__(256, 2)
void gemm_nt_3bf16(const float* __restrict__ A,
                   const float* __restrict__ W0, const float* __restrict__ W1,
                   const float* __restrict__ W2,
                   float* __restrict__ O0, float* __restrict__ O1,
                   float* __restrict__ O2)
{
    const float* Wm = (blockIdx.z == 0) ? W0 : (blockIdx.z == 1 ? W1 : W2);
    float*       O  = (blockIdx.z == 0) ? O0 : (blockIdx.z == 1 ? O1 : O2);

    __shared__ unsigned short Ah[128][40], Al[128][40];   // 2 x 10240 B
    __shared__ unsigned short Bh[128][40], Bl[128][40];   // 2 x 10240 B

    const int tid  = threadIdx.x;
    const int lane = tid & 63;
    const int wv   = tid >> 6;               // 0..3
    const int wm   = wv >> 1, wn = wv & 1;   // 2x2 wave grid
    const int fm   = lane & 15;              // fragment row/col
    const int fq   = lane >> 4;              // k-quad
    const int m0   = blockIdx.y * 128;
    const int n0   = blockIdx.x * 128;

    f32x4 acc[4][4] = {};

    for (int k0 = 0; k0 < Cn; k0 += 32) {
        __syncthreads();
        // stage 128 rows x 32 k of A and W, split hi/lo.  512 8-elem chunks
        // per matrix; 2 per thread per matrix.
#pragma unroll
        for (int r = 0; r < 2; ++r) {
            const int idx = tid + r * 256;
            const int row = idx >> 2, c8 = (idx & 3) * 8;
            {
                const float* s = &A[(size_t)(m0 + row) * Cn + k0 + c8];
                const float4 x0 = *(const float4*)s, x1 = *(const float4*)(s + 4);
                ushort8v h, l;
                bfpair p;
                p = split_bf16(x0.x); h[0] = p.h; l[0] = p.l;
                p = split_bf16(x0.y); h[1] = p.h; l[1] = p.l;
                p = split_bf16(x0.z); h[2] = p.h; l[2] = p.l;
                p = split_bf16(x0.w); h[3] = p.h; l[3] = p.l;
                p = split_bf16(x1.x); h[4] = p.h; l[4] = p.l;
                p = split_bf16(x1.y); h[5] = p.h; l[5] = p.l;
                p = split_bf16(x1.z); h[6] = p.h; l[6] = p.l;
                p = split_bf16(x1.w); h[7] = p.h; l[7] = p.l;
                *(ushort8v*)&Ah[row][c8] = h;
                *(ushort8v*)&Al[row][c8] = l;
            }
            {
                const float* s = &Wm[(size_t)(n0 + row) * Cn + k0 + c8];
                const float4 x0 = *(const float4*)s, x1 = *(const float4*)(s + 4);
                ushort8v h, l;
                bfpair p;
                p = split_bf16(x0.x); h[0] = p.h; l[0] = p.l;
                p = split_bf16(x0.y); h[1] = p.h; l[1] = p.l;
                p = split_bf16(x0.z); h[2] = p.h; l[2] = p.l;
                p = split_bf16(x0.w); h[3] = p.h; l[3] = p.l;
                p = split_bf16(x1.x); h[4] = p.h; l[4] = p.l;
                p = split_bf16(x1.y); h[5] = p.h; l[5] = p.l;
                p = split_bf16(x1.z); h[6] = p.h; l[6] = p.l;
                p = split_bf16(x1.w); h[7] = p.h; l[7] = p.l;
                *(ushort8v*)&Bh[row][c8] = h;
                *(ushort8v*)&Bl[row][c8] = l;
            }
        }
        __syncthreads();

        short8v ah[4], al[4], bh[4], bl[4];
#pragma unroll
        for (int ti = 0; ti < 4; ++ti) {
            ah[ti] = *(const short8v*)&Ah[wm * 64 + ti * 16 + fm][fq * 8];
            al[ti] = *(const short8v*)&Al[wm * 64 + ti * 16 + fm][fq * 8];
            bh[ti] = *(const short8v*)&Bh[wn * 64 + ti * 16 + fm][fq * 8];
            bl[ti] = *(const short8v*)&Bl[wn * 64 + ti * 16 + fm][fq * 8];
        }
#pragma unroll
        for (int ti = 0; ti < 4; ++ti)
#pragma unroll
            for (int tj = 0; tj < 4; ++tj) {
                acc[ti][tj] = __builtin_amdgcn_mfma_f32_16x16x32_bf16(
                    ah[ti], bh[tj], acc[ti][tj], 0, 0, 0);
                acc[ti][tj] = __builtin_amdgcn_mfma_f32_16x16x32_bf16(
                    ah[ti], bl[tj], acc[ti][tj], 0, 0, 0);
                acc[ti][tj] = __builtin_amdgcn_mfma_f32_16x16x32_bf16(
                    al[ti], bh[tj], acc[ti][tj], 0, 0, 0);
            }
    }

#pragma unroll
    for (int ti = 0; ti < 4; ++ti)
#pragma unroll
        for (int tj = 0; tj < 4; ++tj)
#pragma unroll
            for (int r = 0; r < 4; ++r) {
                const int row = m0 + wm * 64 + ti * 16 + fq * 4 + r;
                const int col = n0 + wn * 64 + tj * 16 + fm;
                O[(size_t)row * Cn + col] = acc[ti][tj][r];
            }
}

// ---------------------------------------------------------------------------
// Feature sparsify: per 64-elem head vector keep |v| >= 8th-largest |v|.
// One wave per vector; Q,K,V in-place.  3*65536 vectors total.
// ---------------------------------------------------------------------------
__global__ __launch_bounds__(256)
void sparsify_topk(float* __restrict__ Q, float* __restrict__ K,
                   float* __restrict__ V)
{
    const int wid  = (blockIdx.x * 256 + threadIdx.x) >> 6;  // global wave id
    const int lane = threadIdx.x & 63;
    const int tensor = wid >> 16;        // 65536 vectors per tensor
    const int vec    = wid & 65535;
    float* base = (tensor == 0) ? Q : (tensor == 1 ? K : V);

    const size_t off = (size_t)vec * 64 + lane;
    const float v = base[off];
    const float a = fabsf(v);

    int cnt = 0;   // # strictly greater than mine
#pragma unroll
    for (int j = 0; j < 64; ++j) {
        const float aj = __shfl(a, j);
        cnt += (aj > a) ? 1 : 0;
    }
    float cand = (cnt < FKEEP) ? a : 3.402823466e38f;
#pragma unroll
    for (int o = 32; o; o >>= 1) cand = fminf(cand, __shfl_xor(cand, o));
    base[off] = (a >= cand) ? v : 0.0f;
}

// ---------------------------------------------------------------------------
// Attention core (R6 design, first timed this round).  R4: LDS scores (no
// scratch); R5: radix select + visible-only striping; R6: score-phase K-tile
// register prefetch + PV compaction with 4-deep pipelined coalesced gather.
// All bit-exact vs the R4/R5 canary absmax 0.01391602 in fp32.
// LDS map (dynamic, 151808 B): sc[16][2112] scores | kt[64][65] K tile,
// overlaid after the score phase by hist/ct[16][256] (wave-private rows).
// ---------------------------------------------------------------------------
__global__ __launch_bounds__(1024, 4)
void attn_kernel(const float* __restrict__ Qm, const float* __restrict__ Km,
                 const float* __restrict__ Vm, float* __restrict__ AO)
{
    extern __shared__ unsigned smem[];
    unsigned* sc   = smem;                         // 16*2112 = 33792 words
    float*    kt   = (float*)(smem + 16 * SC_ROW); // 64*65   =  4160 words
    unsigned* hist = smem + 16 * SC_ROW;           // 16*256 overlay (per-wave row)

    const int tid  = threadIdx.x;
    const int w    = tid >> 6;
    const int lane = tid & 63;
    const int bh   = blockIdx.y;         // 0..31
    const int b    = bh >> 4;
    const int h    = bh & 15;
    const int t    = blockIdx.x * 16 + w;
    const size_t rowoff = (size_t)(b * Tn + t) * Cn + h * 64;
    const size_t kvoff  = (size_t)(b * Tn) * Cn + h * 64;

    // ---- init all score rows to umap(-inf) (pads too) ----
#pragma unroll
    for (int i = 0; i < 33; ++i) smem[i * 1024 + tid] = U_NEG_INF;

    // ---- sparse q row in a register; nonzero feature mask in SGPRs ----
    const float q0  = Qm[rowoff + lane];
    const float qsc = q0 * 0.125f;                  // fold 1/sqrt(D)
    const unsigned long long nzm = __ballot(q0 != 0.0f);  // wave-uniform

    unsigned* myrow = sc + w * SC_ROW;
    const int lb = (lane >> 5) * 33 + (lane & 31);  // striped lane base
    unsigned rowmax = 0u;

    // ---- score phase: visible tiles only; next-tile register prefetch ----
    const int ntiles = ((blockIdx.x * 16 + 15) >> 6) + 1;   // block-uniform
    const int stc = tid >> 4, stq = (tid & 15) * 4;         // staging coords
    const float* kbase = &Km[kvoff + (size_t)stc * Cn + stq];
    float4 kreg = *(const float4*)kbase;                    // tile 0
    for (int tk = 0; tk < ntiles; ++tk) {
        const int s0 = tk << 6;
        __syncthreads();                 // prior consumers done (and init on tk==0)
        {
            float* dst = &kt[stc * 65 + stq];
            dst[0] = kreg.x; dst[1] = kreg.y; dst[2] = kreg.z; dst[3] = kreg.w;
        }
        if (tk + 1 < ntiles)             // issue next load; waits overlap compute
            kreg = *(const float4*)(kbase + (size_t)(tk + 1) * 64 * Cn);
        __syncthreads();
        if (s0 <= t) {                   // wave-uniform
            float s = 0.0f;
            unsigned long long mm = nzm;
            while (mm) {                 // nnz (~8) iterations, wave-uniform
                const int m = __builtin_ctzll(mm); mm &= mm - 1;
#if __has_builtin(__builtin_amdgcn_readlane)
                const float qm = __int_as_float(
                    __builtin_amdgcn_readlane(__float_as_int(qsc), m));
#else
                const float qm = __shfl(qsc, m);
#endif
                s += qm * kt[lane * 65 + m];   // banks (lane+m)%32: 2-way, free
            }
            unsigned val = U_NEG_INF;
            if (s0 + lane <= t) val = umap(s);
            myrow[tk * 66 + lb] = val;         // col = s0 + lane
            rowmax = (val > rowmax) ? val : rowmax;
        }
    }
    __syncthreads();    // kt dead from here; hist/ct overlay becomes safe

#pragma unroll
    for (int o = 32; o; o >>= 1) {
        const unsigned m2 = __shfl_xor(rowmax, o);
        rowmax = (m2 > rowmax) ? m2 : rowmax;
    }
    const float fm = uunmap(rowmax);     // row max (finite: col 0 <= t)

    const int nj = (t >> 6) + 1;         // visible striped groups, wave-uniform

    // ---- exact kth via radix-256 select over LDS (wave-local) ----
    unsigned cur = U_NEG_INF;            // rows t<256 keep everything
    if (t >= KKEEP) {
        unsigned* hrow = hist + w * 256;
        unsigned prefix = 0u, pmask = 0u;
        unsigned r = KKEEP;
#pragma unroll 1
        for (int level = 0; level < 4; ++level) {
            const int sh = 24 - 8 * level;
            hrow[lane] = 0; hrow[64 + lane] = 0; hrow[128 + lane] = 0; hrow[192 + lane] = 0;
            __asm__ volatile("s_waitcnt lgkmcnt(0)" ::: "memory");
#pragma unroll 1
            for (int j = 0; j < nj; ++j) {
                const int col = (j << 6) + lane;
                if (col <= t) {
                    const unsigned v = myrow[j * 66 + lb];
                    if ((v & pmask) == prefix)
                        atomicAdd(&hrow[(v >> sh) & 255u], 1u);
                }
            }
            __asm__ volatile("s_waitcnt lgkmcnt(0)" ::: "memory");
            const uint4 hv = *(const uint4*)&hrow[lane * 4];   // bins 4l..4l+3
            const unsigned ls = hv.x + hv.y + hv.z + hv.w;
            unsigned sfx = ls;                    // inclusive suffix over lanes
#pragma unroll
            for (int off = 1; off < 64; off <<= 1) {
                const unsigned tt = __shfl_down(sfx, off);
                if (lane + off < 64) sfx += tt;
            }
            const unsigned excl = sfx - ls;       // lanes strictly above
            const unsigned c3 = excl + hv.w, c2 = c3 + hv.z,
                           c1 = c2 + hv.y,  c0 = c1 + hv.x;
            int bsel = -1; unsigned csel = 0, cnext = 0;
            if      (c3 >= r) { bsel = 4 * lane + 3; csel = c3; cnext = excl; }
            else if (c2 >= r) { bsel = 4 * lane + 2; csel = c2; cnext = c3; }
            else if (c1 >= r) { bsel = 4 * lane + 1; csel = c1; cnext = c2; }
            else if (c0 >= r) { bsel = 4 * lane + 0; csel = c0; cnext = c1; }
            int B = bsel;
#pragma unroll
            for (int off = 32; off; off >>= 1) {
                const int ob = __shfl_xor(B, off);
                B = (ob > B) ? ob : B;
            }
            const unsigned cB  = (unsigned)__shfl((int)csel,  B >> 2);
            const unsigned cB1 = (unsigned)__shfl((int)cnext, B >> 2);
            prefix |= (unsigned)B << sh;
            pmask  |= 255u << sh;
            if (cB == r || level == 3) { cur = prefix; break; }
            r -= cB1;                    // rank within bin B
        }
    }

    // ---- softmax over kept visible entries; write p back ----
    float ps = 0.0f;
#pragma unroll 1
    for (int j = 0; j < nj; ++j) {
        const int col = (j << 6) + lane;
        if (col <= t) {
            const unsigned uv = myrow[j * 66 + lb];
            const float pv = (uv >= cur) ? __expf(uunmap(uv) - fm) : 0.0f;
            myrow[j * 66 + lb] = __float_as_uint(pv);
            ps += pv;
        }
    }
#pragma unroll
    for (int o = 32; o; o >>= 1) ps += __shfl_xor(ps, o);
    const float inv = 1.0f / ps;         // ps >= 1 (row max is kept)

    // ---- compact kept cols into this wave's hist row (<=256) ----
    unsigned* ct = hist + w * 256;       // own row only: no cross-wave hazard
    int cnt = 0; bool ovf = false;
#pragma unroll 1
    for (int g = 0; g < nj; ++g) {
        const int col = (g << 6) + lane;
        const float pv = (col <= t) ? __uint_as_float(myrow[g * 66 + lb]) : 0.0f;
        const unsigned long long m = __ballot(pv > 0.0f);
        const int c = __popcll(m);
        if (cnt + c <= 256) {
            if (pv > 0.0f)
                ct[cnt + __popcll(m & ((1ull << lane) - 1ull))] = (unsigned)col;
        } else ovf = true;
        cnt += c;
    }

    float acc = 0.0f;
    const float* __restrict__ vcol = Vm + kvoff + lane;
    if (!ovf) {
        // pull list into 4 register sections (lane l holds entries blk*64+l)
        int   cR[4]; float pR[4];
#pragma unroll
        for (int blk = 0; blk < 4; ++blk) {
            const int idx = blk * 64 + lane;
            cR[blk] = (idx < cnt) ? (int)ct[idx] : 0;
            pR[blk] = (idx < cnt) ? __uint_as_float(myrow[sc_addr(cR[blk])]) : 0.0f;
        }
        // col-ascending accumulation, 4 independent V loads in flight
#pragma unroll
        for (int blk = 0; blk < 4; ++blk) {
            if (blk * 64 < cnt) {        // wave-uniform
                const int lim = min(64, cnt - blk * 64);
                int j = 0;
                for (; j + 4 <= lim; j += 4) {
                    const int   ca = __shfl(cR[blk], j),     cb = __shfl(cR[blk], j + 1);
                    const int   cc = __shfl(cR[blk], j + 2), cd = __shfl(cR[blk], j + 3);
                    const float pa = __shfl(pR[blk], j),     pb = __shfl(pR[blk], j + 1);
                    const float pc = __shfl(pR[blk], j + 2), pd = __shfl(pR[blk], j + 3);
                    const float va = vcol[(size_t)ca * Cn], vb = vcol[(size_t)cb * Cn];
                    const float vc = vcol[(size_t)cc * Cn], vd = vcol[(size_t)cd * Cn];
                    acc += pa * va; acc += pb * vb; acc += pc * vc; acc += pd * vd;
                }
                for (; j < lim; ++j) {
                    const int   c1 = __shfl(cR[blk], j);
                    const float p1 = __shfl(pR[blk], j);
                    acc += p1 * vcol[(size_t)c1 * Cn];
                }
            }
        }
    } else {
        // tie-overflow fallback (rare): R5's while(ballot) gather
#pragma unroll 1
        for (int g = 0; g < nj; ++g) {
            const int col = (g << 6) + lane;
            const float pv = (col <= t) ? __uint_as_float(myrow[g * 66 + lb]) : 0.0f;
            unsigned long long m = __ballot(pv > 0.0f);
            const int cb = g << 6;
            while (m) {
                const int l0 = __builtin_ctzll(m); m &= m - 1;
                const float w0 = __shfl(pv, l0);
                const float v0 = vcol[(size_t)(cb + l0) * Cn];
                float w1 = 0.0f, v1 = 0.0f;
                if (m) {
                    const int l1 = __builtin_ctzll(m); m &= m - 1;
                    w1 = __shfl(pv, l1);
                    v1 = vcol[(size_t)(cb + l1) * Cn];
                }
                acc += w0 * v0;
                acc += w1 * v1;
            }
        }
    }
    AO[rowoff + lane] = acc * inv;
}

// ---------------------------------------------------------------------------
extern "C" void kernel_launch(void* const* d_in, const int* in_sizes, int n_in,
                              void* d_out, int out_size, void* d_ws, size_t ws_size,
                              hipStream_t stream)
{
    const float* x  = (const float*)d_in[0];
    const float* Wq = (const float*)d_in[1];
    const float* Wk = (const float*)d_in[2];
    const float* Wv = (const float*)d_in[3];
    const float* Wo = (const float*)d_in[4];
    float* out = (float*)d_out;

    float* Q  = (float*)d_ws;            // 4 buffers x 4194304 floats = 64 MB
    float* K  = Q + (size_t)Mn * Cn;
    float* V  = K + (size_t)Mn * Cn;
    float* AO = V + (size_t)Mn * Cn;

    constexpr int ATTN_LDS = (16 * SC_ROW + 64 * 65) * 4;   // 151808 B
    static_assert(ATTN_LDS <= 163840, "LDS over 160 KiB");
    static_assert(16 * 256 <= 64 * 65, "hist/ct overlay exceeds kt region");
    (void)hipFuncSetAttribute((const void*)attn_kernel,
                              hipFuncAttributeMaxDynamicSharedMemorySize, ATTN_LDS);

    // 1) Q/K/V projections (split-bf16 MFMA, ~fp32 accuracy)
    gemm_nt_3bf16<<<dim3(Cn / 128, Mn / 128, 3), 256, 0, stream>>>(
        x, Wq, Wk, Wv, Q, K, V);

    // 2) feature top-8 sparsification, in place
    sparsify_topk<<<dim3(3 * 65536 / 4), 256, 0, stream>>>(Q, K, V);

    // 3) sparse attention core -> AO in [B,T,H,D] (== [B,T,C]) layout
    attn_kernel<<<dim3(Tn / 16, 32), 1024, ATTN_LDS, stream>>>(Q, K, V, AO);

    // 4) output projection (split-bf16 MFMA)
    gemm_nt_3bf16<<<dim3(Cn / 128, Mn / 128, 1), 256, 0, stream>>>(
        AO, Wo, Wo, Wo, out, out, out);
}

// Round 10
// 1220.639 us; speedup vs baseline: 8.0398x; 1.1536x over previous
//
#include <hip/hip_runtime.h>
#include <cstdint>

// Problem constants: B=2, T=2048, C=1024, H=16, D=64, TOP_K=256
// feat_keep = ceil(D*min(TOP_K,T)/T) = ceil(64*256/2048) = 8
constexpr int Tn = 2048;
constexpr int Cn = 1024;
constexpr int Mn = 4096;          // B*T
constexpr int KKEEP = 256;        // row-wise top-k
constexpr int FKEEP = 8;          // feature top-k
constexpr unsigned U_NEG_INF = 0x007FFFFFu;  // umap(-inf)

// Score row layout in LDS: 64 chunks of 33 words (32 cols + 1 pad).
// Striped access col = j*64+lane -> addr = j*66 + lane_base: <=2-way banks.
constexpr int SC_ROW = 64 * 33;   // 2112 words per query row
__device__ __forceinline__ int sc_addr(int col) { return (col >> 5) * 33 + (col & 31); }

// Order-preserving fp32 -> uint32 map (monotonic incl. +-inf; no NaNs here).
__device__ __forceinline__ unsigned umap(float f) {
    unsigned b = __float_as_uint(f);
    return (b & 0x80000000u) ? ~b : (b | 0x80000000u);
}
__device__ __forceinline__ float uunmap(unsigned u) {
    return __uint_as_float((u & 0x80000000u) ? (u ^ 0x80000000u) : ~u);
}

// fp32 -> bf16 (RNE).
__device__ __forceinline__ unsigned short f2bf(float f) {
    unsigned u = __float_as_uint(f);
    u += 0x7FFFu + ((u >> 16) & 1u);
    return (unsigned short)(u >> 16);
}
// Split fp32 into hi+lo bf16 pair (by value: ext-vector elems can't bind to
// non-const refs — R7).  x ~= hi + lo, ~17-bit effective mantissa.
struct bfpair { unsigned short h, l; };
__device__ __forceinline__ bfpair split_bf16(float x) {
    bfpair r;
    r.h = f2bf(x);
    r.l = f2bf(x - __uint_as_float((unsigned)r.h << 16));
    return r;
}

// Wave-uniform broadcasts on the SALU path (NOT ds_bpermute / LDS pipe).
__device__ __forceinline__ int   rli(int v, int l)   { return __builtin_amdgcn_readlane(v, l); }
__device__ __forceinline__ float rlf(float v, int l) {
    return __int_as_float(__builtin_amdgcn_readlane(__float_as_int(v), l));
}

typedef __attribute__((ext_vector_type(8))) short          short8v;  // 8 bf16
typedef __attribute__((ext_vector_type(8))) unsigned short ushort8v;
typedef __attribute__((ext_vector_type(4))) float          f32x4;    // MFMA acc

// ---------------------------------------------------------------------------
// Split-bf16 MFMA GEMM ("3xBF16"): O[m][n] = sum_k A[m][k] * W[n][k],
// fp32 in/out at ~fp32 accuracy (R8: reproduces the fp32 canary absmax
// exactly).  acc += Ah*Bh + Ah*Bl + Al*Bh (lo*lo ~2^-18, dropped).
// 128x128 tile, BK=32, 256 thr = 4 waves (2x2), 4x4 16x16x32 MFMAs per wave.
// LDS rows padded to 40 ushorts (80 B stride -> <=2-way banks).
// blockIdx.z selects W/O (z=3 for QKV, z=1 for out-proj).
// ---------------------------------------------------------------------------
__global__ __launch_bounds__(256, 2)
void gemm_nt_3bf16(const float* __restrict__ A,
                   const float* __restrict__ W0, const float* __restrict__ W1,
                   const float* __restrict__ W2,
                   float* __restrict__ O0, float* __restrict__ O1,
                   float* __restrict__ O2)
{
    const float* Wm = (blockIdx.z == 0) ? W0 : (blockIdx.z == 1 ? W1 : W2);
    float*       O  = (blockIdx.z == 0) ? O0 : (blockIdx.z == 1 ? O1 : O2);

    __shared__ unsigned short Ah[128][40], Al[128][40];   // 2 x 10240 B
    __shared__ unsigned short Bh[128][40], Bl[128][40];   // 2 x 10240 B

    const int tid  = threadIdx.x;
    const int lane = tid & 63;
    const int wv   = tid >> 6;               // 0..3
    const int wm   = wv >> 1, wn = wv & 1;   // 2x2 wave grid
    const int fm   = lane & 15;              // fragment row/col
    const int fq   = lane >> 4;              // k-quad
    const int m0   = blockIdx.y * 128;
    const int n0   = blockIdx.x * 128;

    f32x4 acc[4][4] = {};

    for (int k0 = 0; k0 < Cn; k0 += 32) {
        __syncthreads();
        // stage 128 rows x 32 k of A and W, split hi/lo.  512 8-elem chunks
        // per matrix; 2 per thread per matrix.
#pragma unroll
        for (int r = 0; r < 2; ++r) {
            const int idx = tid + r * 256;
            const int row = idx >> 2, c8 = (idx & 3) * 8;
            {
                const float* s = &A[(size_t)(m0 + row) * Cn + k0 + c8];
                const float4 x0 = *(const float4*)s, x1 = *(const float4*)(s + 4);
                ushort8v h, l;
                bfpair p;
                p = split_bf16(x0.x); h[0] = p.h; l[0] = p.l;
                p = split_bf16(x0.y); h[1] = p.h; l[1] = p.l;
                p = split_bf16(x0.z); h[2] = p.h; l[2] = p.l;
                p = split_bf16(x0.w); h[3] = p.h; l[3] = p.l;
                p = split_bf16(x1.x); h[4] = p.h; l[4] = p.l;
                p = split_bf16(x1.y); h[5] = p.h; l[5] = p.l;
                p = split_bf16(x1.z); h[6] = p.h; l[6] = p.l;
                p = split_bf16(x1.w); h[7] = p.h; l[7] = p.l;
                *(ushort8v*)&Ah[row][c8] = h;
                *(ushort8v*)&Al[row][c8] = l;
            }
            {
                const float* s = &Wm[(size_t)(n0 + row) * Cn + k0 + c8];
                const float4 x0 = *(const float4*)s, x1 = *(const float4*)(s + 4);
                ushort8v h, l;
                bfpair p;
                p = split_bf16(x0.x); h[0] = p.h; l[0] = p.l;
                p = split_bf16(x0.y); h[1] = p.h; l[1] = p.l;
                p = split_bf16(x0.z); h[2] = p.h; l[2] = p.l;
                p = split_bf16(x0.w); h[3] = p.h; l[3] = p.l;
                p = split_bf16(x1.x); h[4] = p.h; l[4] = p.l;
                p = split_bf16(x1.y); h[5] = p.h; l[5] = p.l;
                p = split_bf16(x1.z); h[6] = p.h; l[6] = p.l;
                p = split_bf16(x1.w); h[7] = p.h; l[7] = p.l;
                *(ushort8v*)&Bh[row][c8] = h;
                *(ushort8v*)&Bl[row][c8] = l;
            }
        }
        __syncthreads();

        short8v ah[4], al[4], bh[4], bl[4];
#pragma unroll
        for (int ti = 0; ti < 4; ++ti) {
            ah[ti] = *(const short8v*)&Ah[wm * 64 + ti * 16 + fm][fq * 8];
            al[ti] = *(const short8v*)&Al[wm * 64 + ti * 16 + fm][fq * 8];
            bh[ti] = *(const short8v*)&Bh[wn * 64 + ti * 16 + fm][fq * 8];
            bl[ti] = *(const short8v*)&Bl[wn * 64 + ti * 16 + fm][fq * 8];
        }
#pragma unroll
        for (int ti = 0; ti < 4; ++ti)
#pragma unroll
            for (int tj = 0; tj < 4; ++tj) {
                acc[ti][tj] = __builtin_amdgcn_mfma_f32_16x16x32_bf16(
                    ah[ti], bh[tj], acc[ti][tj], 0, 0, 0);
                acc[ti][tj] = __builtin_amdgcn_mfma_f32_16x16x32_bf16(
                    ah[ti], bl[tj], acc[ti][tj], 0, 0, 0);
                acc[ti][tj] = __builtin_amdgcn_mfma_f32_16x16x32_bf16(
                    al[ti], bh[tj], acc[ti][tj], 0, 0, 0);
            }
    }

#pragma unroll
    for (int ti = 0; ti < 4; ++ti)
#pragma unroll
        for (int tj = 0; tj < 4; ++tj)
#pragma unroll
            for (int r = 0; r < 4; ++r) {
                const int row = m0 + wm * 64 + ti * 16 + fq * 4 + r;
                const int col = n0 + wn * 64 + tj * 16 + fm;
                O[(size_t)row * Cn + col] = acc[ti][tj][r];
            }
}

// ---------------------------------------------------------------------------
// Feature sparsify: per 64-elem head vector keep |v| >= 8th-largest |v|.
// One wave per vector; Q,K,V in-place.  3*65536 vectors total.
// ---------------------------------------------------------------------------
__global__ __launch_bounds__(256)
void sparsify_topk(float* __restrict__ Q, float* __restrict__ K,
                   float* __restrict__ V)
{
    const int wid  = (blockIdx.x * 256 + threadIdx.x) >> 6;  // global wave id
    const int lane = threadIdx.x & 63;
    const int tensor = wid >> 16;        // 65536 vectors per tensor
    const int vec    = wid & 65535;
    float* base = (tensor == 0) ? Q : (tensor == 1 ? K : V);

    const size_t off = (size_t)vec * 64 + lane;
    const float v = base[off];
    const float a = fabsf(v);

    int cnt = 0;   // # strictly greater than mine
#pragma unroll
    for (int j = 0; j < 64; ++j) {
        const float aj = __shfl(a, j);
        cnt += (aj > a) ? 1 : 0;
    }
    float cand = (cnt < FKEEP) ? a : 3.402823466e38f;
#pragma unroll
    for (int o = 32; o; o >>= 1) cand = fminf(cand, __shfl_xor(cand, o));
    base[off] = (a >= cand) ? v : 0.0f;
}

// ---------------------------------------------------------------------------
// Attention core, R10 (= R9 with the PV lambda type bug fixed: blk_p was
// declared `int`, silently truncating every float probability to 0 —
// absmax 0.90).  PV broadcasts via __builtin_amdgcn_readlane with
// compile-time lane index (SALU path) instead of __shfl(runtime j) which
// lowers to ds_bpermute (LDS pipe, 512 ops/row — R8 post-mortem).
// Branchless tail: entries >= cnt have p=0,c=0 -> acc += 0*V[0], bit-exact.
// LDS map (dynamic, 151808 B): sc[16][2112] scores | kt[64][65] K tile,
// overlaid after the score phase by hist/ct[16][256] (wave-private rows).
// ---------------------------------------------------------------------------
__global__ __launch_bounds__(1024, 4)
void attn_kernel(const float* __restrict__ Qm, const float* __restrict__ Km,
                 const float* __restrict__ Vm, float* __restrict__ AO)
{
    extern __shared__ unsigned smem[];
    unsigned* sc   = smem;                         // 16*2112 = 33792 words
    float*    kt   = (float*)(smem + 16 * SC_ROW); // 64*65   =  4160 words
    unsigned* hist = smem + 16 * SC_ROW;           // 16*256 overlay (per-wave row)

    const int tid  = threadIdx.x;
    const int w    = tid >> 6;
    const int lane = tid & 63;
    const int bh   = blockIdx.y;         // 0..31
    const int b    = bh >> 4;
    const int h    = bh & 15;
    const int t    = blockIdx.x * 16 + w;
    const size_t rowoff = (size_t)(b * Tn + t) * Cn + h * 64;
    const size_t kvoff  = (size_t)(b * Tn) * Cn + h * 64;

    // ---- init all score rows to umap(-inf) (pads too) ----
#pragma unroll
    for (int i = 0; i < 33; ++i) smem[i * 1024 + tid] = U_NEG_INF;

    // ---- sparse q row in a register; nonzero feature mask in SGPRs ----
    const float q0  = Qm[rowoff + lane];
    const float qsc = q0 * 0.125f;                  // fold 1/sqrt(D)
    const unsigned long long nzm = __ballot(q0 != 0.0f);  // wave-uniform

    unsigned* myrow = sc + w * SC_ROW;
    const int lb = (lane >> 5) * 33 + (lane & 31);  // striped lane base
    unsigned rowmax = 0u;

    // ---- score phase: visible tiles only; next-tile register prefetch ----
    const int ntiles = ((blockIdx.x * 16 + 15) >> 6) + 1;   // block-uniform
    const int stc = tid >> 4, stq = (tid & 15) * 4;         // staging coords
    const float* kbase = &Km[kvoff + (size_t)stc * Cn + stq];
    float4 kreg = *(const float4*)kbase;                    // tile 0
    for (int tk = 0; tk < ntiles; ++tk) {
        const int s0 = tk << 6;
        __syncthreads();                 // prior consumers done (and init on tk==0)
        {
            float* dst = &kt[stc * 65 + stq];
            dst[0] = kreg.x; dst[1] = kreg.y; dst[2] = kreg.z; dst[3] = kreg.w;
        }
        if (tk + 1 < ntiles)             // issue next load; waits overlap compute
            kreg = *(const float4*)(kbase + (size_t)(tk + 1) * 64 * Cn);
        __syncthreads();
        if (s0 <= t) {                   // wave-uniform
            float s = 0.0f;
            unsigned long long mm = nzm;
            while (mm) {                 // nnz (~8) iterations, wave-uniform
                const int m = __builtin_ctzll(mm); mm &= mm - 1;
                const float qm = __int_as_float(
                    __builtin_amdgcn_readlane(__float_as_int(qsc), m));
                s += qm * kt[lane * 65 + m];   // banks (lane+m)%32: 2-way, free
            }
            unsigned val = U_NEG_INF;
            if (s0 + lane <= t) val = umap(s);
            myrow[tk * 66 + lb] = val;         // col = s0 + lane
            rowmax = (val > rowmax) ? val : rowmax;
        }
    }
    __syncthreads();    // kt dead from here; hist/ct overlay becomes safe

#pragma unroll
    for (int o = 32; o; o >>= 1) {
        const unsigned m2 = __shfl_xor(rowmax, o);
        rowmax = (m2 > rowmax) ? m2 : rowmax;
    }
    const float fm = uunmap(rowmax);     // row max (finite: col 0 <= t)

    const int nj = (t >> 6) + 1;         // visible striped groups, wave-uniform

    // ---- exact kth via radix-256 select over LDS (wave-local) ----
    unsigned cur = U_NEG_INF;            // rows t<256 keep everything
    if (t >= KKEEP) {
        unsigned* hrow = hist + w * 256;
        unsigned prefix = 0u, pmask = 0u;
        unsigned r = KKEEP;
#pragma unroll 1
        for (int level = 0; level < 4; ++level) {
            const int sh = 24 - 8 * level;
            hrow[lane] = 0; hrow[64 + lane] = 0; hrow[128 + lane] = 0; hrow[192 + lane] = 0;
            __asm__ volatile("s_waitcnt lgkmcnt(0)" ::: "memory");
#pragma unroll 1
            for (int j = 0; j < nj; ++j) {
                const int col = (j << 6) + lane;
                if (col <= t) {
                    const unsigned v = myrow[j * 66 + lb];
                    if ((v & pmask) == prefix)
                        atomicAdd(&hrow[(v >> sh) & 255u], 1u);
                }
            }
            __asm__ volatile("s_waitcnt lgkmcnt(0)" ::: "memory");
            const uint4 hv = *(const uint4*)&hrow[lane * 4];   // bins 4l..4l+3
            const unsigned ls = hv.x + hv.y + hv.z + hv.w;
            unsigned sfx = ls;                    // inclusive suffix over lanes
#pragma unroll
            for (int off = 1; off < 64; off <<= 1) {
                const unsigned tt = __shfl_down(sfx, off);
                if (lane + off < 64) sfx += tt;
            }
            const unsigned excl = sfx - ls;       // lanes strictly above
            const unsigned c3 = excl + hv.w, c2 = c3 + hv.z,
                           c1 = c2 + hv.y,  c0 = c1 + hv.x;
            int bsel = -1; unsigned csel = 0, cnext = 0;
            if      (c3 >= r) { bsel = 4 * lane + 3; csel = c3; cnext = excl; }
            else if (c2 >= r) { bsel = 4 * lane + 2; csel = c2; cnext = c3; }
            else if (c1 >= r) { bsel = 4 * lane + 1; csel = c1; cnext = c2; }
            else if (c0 >= r) { bsel = 4 * lane + 0; csel = c0; cnext = c1; }
            int B = bsel;
#pragma unroll
            for (int off = 32; off; off >>= 1) {
                const int ob = __shfl_xor(B, off);
                B = (ob > B) ? ob : B;
            }
            const unsigned cB  = (unsigned)__shfl((int)csel,  B >> 2);
            const unsigned cB1 = (unsigned)__shfl((int)cnext, B >> 2);
            prefix |= (unsigned)B << sh;
            pmask  |= 255u << sh;
            if (cB == r || level == 3) { cur = prefix; break; }
            r -= cB1;                    // rank within bin B
        }
    }

    // ---- softmax over kept visible entries; write p back ----
    float ps = 0.0f;
#pragma unroll 1
    for (int j = 0; j < nj; ++j) {
        const int col = (j << 6) + lane;
        if (col <= t) {
            const unsigned uv = myrow[j * 66 + lb];
            const float pv = (uv >= cur) ? __expf(uunmap(uv) - fm) : 0.0f;
            myrow[j * 66 + lb] = __float_as_uint(pv);
            ps += pv;
        }
    }
#pragma unroll
    for (int o = 32; o; o >>= 1) ps += __shfl_xor(ps, o);
    const float inv = 1.0f / ps;         // ps >= 1 (row max is kept)

    // ---- compact kept cols into this wave's hist row (<=256) ----
    unsigned* ct = hist + w * 256;       // own row only: no cross-wave hazard
    int cnt = 0; bool ovf = false;
#pragma unroll 1
    for (int g = 0; g < nj; ++g) {
        const int col = (g << 6) + lane;
        const float pv = (col <= t) ? __uint_as_float(myrow[g * 66 + lb]) : 0.0f;
        const unsigned long long m = __ballot(pv > 0.0f);
        const int c = __popcll(m);
        if (cnt + c <= 256) {
            if (pv > 0.0f)
                ct[cnt + __popcll(m & ((1ull << lane) - 1ull))] = (unsigned)col;
        } else ovf = true;
        cnt += c;
    }

    float acc = 0.0f;
    const float* __restrict__ vcol = Vm + kvoff + lane;
    if (!ovf) {
        // lane l holds list entries blk*64+l; entries >= cnt: c=0, p=0.
        int   cR[4]; float pR[4];
#pragma unroll
        for (int blk = 0; blk < 4; ++blk) {
            const int idx = blk * 64 + lane;
            cR[blk] = (idx < cnt) ? (int)ct[idx] : 0;
            pR[blk] = (idx < cnt) ? __uint_as_float(myrow[sc_addr(cR[blk])]) : 0.0f;
        }
        // Broadcast via readlane (SALU), 4 independent loads per group.
        // Branchless within a 64-block; wave-uniform skip per block.
        // NOTE: blk_p MUST be float (R9: `int blk_p` truncated all p to 0).
        auto do_blk = [&](int blk_c, float blk_p) {
#pragma unroll
            for (int j = 0; j < 64; j += 4) {
                const int   ca = rli(blk_c, j + 0), cb = rli(blk_c, j + 1);
                const int   cc = rli(blk_c, j + 2), cd = rli(blk_c, j + 3);
                const float pa = rlf(blk_p, j + 0), pb = rlf(blk_p, j + 1);
                const float pc = rlf(blk_p, j + 2), pd = rlf(blk_p, j + 3);
                const float va = vcol[(size_t)ca * Cn], vb = vcol[(size_t)cb * Cn];
                const float vc = vcol[(size_t)cc * Cn], vd = vcol[(size_t)cd * Cn];
                acc += pa * va; acc += pb * vb; acc += pc * vc; acc += pd * vd;
            }
        };
        do_blk(cR[0], pR[0]);
        if (cnt > 64)  do_blk(cR[1], pR[1]);
        if (cnt > 128) do_blk(cR[2], pR[2]);
        if (cnt > 192) do_blk(cR[3], pR[3]);
    } else {
        // tie-overflow fallback (rare): while(ballot) gather
#pragma unroll 1
        for (int g = 0; g < nj; ++g) {
            const int col = (g << 6) + lane;
            const float pv = (col <= t) ? __uint_as_float(myrow[g * 66 + lb]) : 0.0f;
            unsigned long long m = __ballot(pv > 0.0f);
            const int cb = g << 6;
            while (m) {
                const int l0 = __builtin_ctzll(m); m &= m - 1;
                const float w0 = __shfl(pv, l0);
                const float v0 = vcol[(size_t)(cb + l0) * Cn];
                float w1 = 0.0f, v1 = 0.0f;
                if (m) {
                    const int l1 = __builtin_ctzll(m); m &= m - 1;
                    w1 = __shfl(pv, l1);
                    v1 = vcol[(size_t)(cb + l1) * Cn];
                }
                acc += w0 * v0;
                acc += w1 * v1;
            }
        }
    }
    AO[rowoff + lane] = acc * inv;
}

// ---------------------------------------------------------------------------
extern "C" void kernel_launch(void* const* d_in, const int* in_sizes, int n_in,
                              void* d_out, int out_size, void* d_ws, size_t ws_size,
                              hipStream_t stream)
{
    const float* x  = (const float*)d_in[0];
    const float* Wq = (const float*)d_in[1];
    const float* Wk = (const float*)d_in[2];
    const float* Wv = (const float*)d_in[3];
    const float* Wo = (const float*)d_in[4];
    float* out = (float*)d_out;

    float* Q  = (float*)d_ws;            // 4 buffers x 4194304 floats = 64 MB
    float* K  = Q + (size_t)Mn * Cn;
    float* V  = K + (size_t)Mn * Cn;
    float* AO = V + (size_t)Mn * Cn;

    constexpr int ATTN_LDS = (16 * SC_ROW + 64 * 65) * 4;   // 151808 B
    static_assert(ATTN_LDS <= 163840, "LDS over 160 KiB");
    static_assert(16 * 256 <= 64 * 65, "hist/ct overlay exceeds kt region");
    (void)hipFuncSetAttribute((const void*)attn_kernel,
                              hipFuncAttributeMaxDynamicSharedMemorySize, ATTN_LDS);

    // 1) Q/K/V projections (split-bf16 MFMA, ~fp32 accuracy)
    gemm_nt_3bf16<<<dim3(Cn / 128, Mn / 128, 3), 256, 0, stream>>>(
        x, Wq, Wk, Wv, Q, K, V);

    // 2) feature top-8 sparsification, in place
    sparsify_topk<<<dim3(3 * 65536 / 4), 256, 0, stream>>>(Q, K, V);

    // 3) sparse attention core -> AO in [B,T,H,D] (== [B,T,C]) layout
    attn_kernel<<<dim3(Tn / 16, 32), 1024, ATTN_LDS, stream>>>(Q, K, V, AO);

    // 4) output projection (split-bf16 MFMA)
    gemm_nt_3bf16<<<dim3(Cn / 128, Mn / 128, 1), 256, 0, stream>>>(
        AO, Wo, Wo, Wo, out, out, out);
}